// Round 7
// baseline (3391.891 us; speedup 1.0000x reference)
//
#include <hip/hip_runtime.h>
#include <cstdint>
#include <cstddef>

// DecoderLSTM: 2-layer LSTM (B=512,H=512,T=128) + 3-layer MLP head.
// fp16 datapath, fp32 accum + fp32 cell state. K-split pipelining (round 5):
// gates_s = X_s@Wx + H_s@Wh; H-half computed one dispatch early by 256 partial
// blocks while 256 completion blocks finish the current step (512 blocks, 2/CU).
// Round 7: (a) W-operand loaded global->VGPR (2-deep reg dbuf, L2-hot) — W no
// longer passes through LDS (halves LDS-pipe traffic); (b) epilogue gate
// regrouping via in-register 4x4 shfl_xor transpose (no sG roundtrip, no
// epilogue barriers); (c) s_setprio around MFMA clusters.

using u16 = unsigned short;
typedef __attribute__((ext_vector_type(8))) _Float16 f16x8;
typedef __attribute__((ext_vector_type(4))) float f32x4;

__device__ __forceinline__ u16 f2h(float f) {
    union { _Float16 h; u16 u; } v; v.h = (_Float16)f; return v.u;
}
__device__ __forceinline__ float h2f(u16 u) {
    union { u16 u; _Float16 h; } v; v.u = u; return (float)v.h;
}
__device__ __forceinline__ float tanh_fast(float v) {
    float a = fabsf(v);
    float t = __expf(-2.f * a);
    float r = (1.f - t) / (1.f + t);
    return copysignf(r, v);
}
__device__ __forceinline__ float sigmoid_fast(float v) {
    return 1.f / (1.f + __expf(-v));
}

__device__ __forceinline__ void gl_lds16(const u16* g, char* l) {
    __builtin_amdgcn_global_load_lds((const __attribute__((address_space(1))) char*)(const char*)g,
                                     (__attribute__((address_space(3))) char*)l, 16, 0, 0);
}

// Swizzled LDS read: tile [64 rows][64 f16] linear (128B rows = 8 x 16B units),
// unit u' holds global col-unit u'^(row&7). Involution applied to global src on
// stage and to the read index here (both sides, rule #21).
__device__ __forceinline__ f16x8 lds_read_sw(const u16* tile, int row, int cu) {
    int unit = (row << 3) | (cu ^ (row & 7));
    return *(const f16x8*)&tile[unit << 3];
}

// ---------------------------------------------------------------- prepack ----
// Bpack[l][np][k] (f16), np = hcol*4 + gate (i,f,g,o), k: 0..511 = W_ih, 512..1023 = W_hh
__global__ __launch_bounds__(256) void prepack(
    const float* __restrict__ W_ih, const float* __restrict__ W_hh,
    const float* __restrict__ b_ih, const float* __restrict__ b_hh,
    const float* __restrict__ fc1w, const float* __restrict__ fc2w, const float* __restrict__ fc3w,
    u16* __restrict__ Bpack, float* __restrict__ bsumv, u16* __restrict__ fcw)
{
    int stride = gridDim.x * blockDim.x;
    int tid0 = blockIdx.x * blockDim.x + threadIdx.x;
    for (int idx = tid0; idx < 2 * 2048 * 1024; idx += stride) {
        int l = idx >> 21;
        int rem = idx & ((1 << 21) - 1);
        int np = rem >> 10;
        int k = rem & 1023;
        int n = (np & 3) * 512 + (np >> 2);
        float v = (k < 512) ? W_ih[((size_t)l * 2048 + n) * 512 + k]
                            : W_hh[((size_t)l * 2048 + n) * 512 + (k - 512)];
        Bpack[idx] = f2h(v);
    }
    for (int idx = tid0; idx < 2 * 2048; idx += stride) {
        int l = idx >> 11;
        int np = idx & 2047;
        int n = (np & 3) * 512 + (np >> 2);
        bsumv[idx] = b_ih[l * 2048 + n] + b_hh[l * 2048 + n];
    }
    for (int idx = tid0; idx < 3 * 512 * 512; idx += stride) {
        const float* w = idx < 262144 ? fc1w : (idx < 524288 ? fc2w : fc3w);
        fcw[idx] = f2h(w[idx & 262143]);
    }
}

// A buffers: [512][1024] f16: cols [0:512) = X (x / hsum / h0-as-X), [512:1024) = h
__global__ __launch_bounds__(256) void initbufs(
    const float* __restrict__ x, u16* __restrict__ A0_0, u16* __restrict__ A1_0,
    float* __restrict__ c0, float* __restrict__ c1, float* __restrict__ gb0)
{
    int stride = gridDim.x * blockDim.x;
    int tid0 = blockIdx.x * blockDim.x + threadIdx.x;
    for (int idx = tid0; idx < 512 * 512; idx += stride) {
        int row = idx >> 9, col = idx & 511;
        size_t b = (size_t)row * 1024;
        A0_0[b + col] = f2h(x[idx]);
        A1_0[b + 512 + col] = 0;     // h1(-1) = 0
        c0[idx] = 0.f;
        c1[idx] = 0.f;
    }
    for (int idx = tid0; idx < 1048576; idx += stride) gb0[idx] = 0.f;  // H-half of step 0
}

// --------------------------------------------------------------- lstm phase --
// 512 blocks x 256 thr (2/CU). Blocks 0..255: completion (gates = gbufR + X@W_x,
// epilogue). Blocks 256..511: partial for NEXT sub-step (gbufW = H@W_h).
// Per role: 64 rows x 64 n'-cols, K=512 in 8 fully-unrolled chunks of 64.
// A staged via swizzled gl_lds (3 bufs x 8KB); W loaded global->VGPR (2-deep
// register double-buffer, L2-hot). Counted vmcnt(6) keeps A(c+1)+W(c) in flight.
template <int IS_L1>
__global__ __launch_bounds__(256) void lstm_phase(
    const u16* __restrict__ Ax, const u16* __restrict__ Ah, int hoffH,
    const u16* __restrict__ Wc, const u16* __restrict__ Wp,
    const float* __restrict__ gbufR, float* __restrict__ gbufW,
    const float* __restrict__ bsumv, float* __restrict__ cbuf,
    u16* __restrict__ hdst, const u16* __restrict__ h0src,
    u16* __restrict__ hsumdst, u16* __restrict__ seqdst)
{
    __shared__ char smem[24576];   // 3 bufs x 8KB (A only)

    const int id = blockIdx.x;
    const bool isPartial = id >= 256;
    const int rid = id & 255;
    const int xcd = rid & 7, slot = rid >> 3;
    const int nb = xcd * 4 + (slot & 3);   // 0..31
    const int rg = slot >> 2;              // 0..7
    const int n0 = nb * 64;
    const int row0 = rg * 64;
    const int tile = rg * 32 + nb;

    const u16* Abase = isPartial ? Ah : Ax;
    const int xoff = isPartial ? hoffH : 0;
    const u16* Wbase = isPartial ? Wp : Wc;

    const int tid = threadIdx.x;
    const int lane = tid & 63, wid = tid >> 6;
    const int wm = (wid >> 1) * 32, wn = (wid & 1) * 32;
    const int fm = lane & 15, q = lane >> 4;

    // A staging: wave w stages 16B-units [w*128, w*128+128); global src pre-swizzled
    const int s0 = wid * 128 + lane, s1 = s0 + 64;
    const int r0s = s0 >> 3, c0s = ((s0 & 7) ^ (r0s & 7)) << 3;
    const int r1s = s1 >> 3, c1s = ((s1 & 7) ^ (r1s & 7)) << 3;
    const size_t aO0 = (size_t)(row0 + r0s) * 1024 + xoff + c0s;
    const size_t aO1 = (size_t)(row0 + r1s) * 1024 + xoff + c1s;
    const int d0 = wid * 2048, d1 = d0 + 1024;

    // W direct-from-global pointers (per-lane fragment rows)
    const u16* pwA = Wbase + (size_t)(n0 + wn + fm) * 1024 + q * 8;       // b0 rows
    const u16* pwB = pwA + 16 * 1024;                                     // b1 rows

    f32x4 acc[2][2];
    acc[0][0] = (f32x4)0.f; acc[0][1] = (f32x4)0.f;
    acc[1][0] = (f32x4)0.f; acc[1][1] = (f32x4)0.f;

    auto stage = [&](char* buf, int k0) {
        gl_lds16(Abase + aO0 + k0, buf + d0);
        gl_lds16(Abase + aO1 + k0, buf + d1);
    };

    char* bufp[3] = { smem, smem + 8192, smem + 16384 };

    // W register double-buffer (static indices via full unroll)
    f16x8 w00[2], w01[2], w10[2], w11[2];

    // prologue: A chunks 0,1 staged; W chunk 0 loaded
    stage(bufp[0], 0);
    stage(bufp[1], 64);
    w00[0] = *(const f16x8*)(pwA + 0);
    w10[0] = *(const f16x8*)(pwA + 32);
    w01[0] = *(const f16x8*)(pwB + 0);
    w11[0] = *(const f16x8*)(pwB + 32);

#pragma unroll
    for (int c = 0; c < 8; ++c) {
        // wait: chunk c's A-stage landed (allow A(c+1):2 + W(c):4 in flight)
        if (c < 7) asm volatile("s_waitcnt vmcnt(6)" ::: "memory");
        else       asm volatile("s_waitcnt vmcnt(4)" ::: "memory");
        __builtin_amdgcn_s_barrier();
        if (c + 2 < 8) stage(bufp[(c + 2) % 3], (c + 2) * 64);
        if (c + 1 < 8) {
            const int k = (c + 1) * 64;
            const int p = (c + 1) & 1;
            w00[p] = *(const f16x8*)(pwA + k);
            w10[p] = *(const f16x8*)(pwA + k + 32);
            w01[p] = *(const f16x8*)(pwB + k);
            w11[p] = *(const f16x8*)(pwB + k + 32);
        }
        __builtin_amdgcn_sched_barrier(0);

        const u16* sA = (const u16*)bufp[c % 3];
        const int p = c & 1;

        f16x8 a00 = lds_read_sw(sA, wm + fm, q);
        f16x8 a10 = lds_read_sw(sA, wm + 16 + fm, q);
        f16x8 a01 = lds_read_sw(sA, wm + fm, 4 + q);
        f16x8 a11 = lds_read_sw(sA, wm + 16 + fm, 4 + q);

        __builtin_amdgcn_s_setprio(1);
        acc[0][0] = __builtin_amdgcn_mfma_f32_16x16x32_f16(a00, w00[p], acc[0][0], 0, 0, 0);
        acc[0][1] = __builtin_amdgcn_mfma_f32_16x16x32_f16(a00, w01[p], acc[0][1], 0, 0, 0);
        acc[1][0] = __builtin_amdgcn_mfma_f32_16x16x32_f16(a10, w00[p], acc[1][0], 0, 0, 0);
        acc[1][1] = __builtin_amdgcn_mfma_f32_16x16x32_f16(a10, w01[p], acc[1][1], 0, 0, 0);
        acc[0][0] = __builtin_amdgcn_mfma_f32_16x16x32_f16(a01, w10[p], acc[0][0], 0, 0, 0);
        acc[0][1] = __builtin_amdgcn_mfma_f32_16x16x32_f16(a01, w11[p], acc[0][1], 0, 0, 0);
        acc[1][0] = __builtin_amdgcn_mfma_f32_16x16x32_f16(a11, w10[p], acc[1][0], 0, 0, 0);
        acc[1][1] = __builtin_amdgcn_mfma_f32_16x16x32_f16(a11, w11[p], acc[1][1], 0, 0, 0);
        __builtin_amdgcn_s_setprio(0);
    }

    // ---------------- partial role: dump fragments to gbufW, done --------------
    if (isPartial) {
        float* dst = gbufW + (size_t)tile * 4096 + wid * 1024 + lane * 4;
        *(f32x4*)(dst +   0) = acc[0][0];
        *(f32x4*)(dst + 256) = acc[0][1];
        *(f32x4*)(dst + 512) = acc[1][0];
        *(f32x4*)(dst + 768) = acc[1][1];
        return;
    }

    // ---------------- completion role: add partial, LSTM epilogue --------------
    {
        const float* src = gbufR + (size_t)tile * 4096 + wid * 1024 + lane * 4;
        acc[0][0] += *(const f32x4*)(src +   0);
        acc[0][1] += *(const f32x4*)(src + 256);
        acc[1][0] += *(const f32x4*)(src + 512);
        acc[1][1] += *(const f32x4*)(src + 768);
    }

    // In-register gate regroup: 4x4 transpose over (lane-quad j, reg r) per frag.
    // After transpose, lane (q, fm=4*hcl+j) holds gates i,f,g,o of cell
    // (row = wm + m*16 + q*4 + j, hc = (n0+wn)/4 + n*4 + hcl).
    const int j = fm & 3;
    const int hcl = fm >> 2;
#pragma unroll
    for (int m = 0; m < 2; ++m)
#pragma unroll
    for (int n = 0; n < 2; ++n) {
        float v0 = acc[m][n][0], v1 = acc[m][n][1], v2 = acc[m][n][2], v3 = acc[m][n][3];
        // stage 1 (xor 1): new[r] = ((j^r)&1) ? M[j^1][r^1] : M[j][r]
        float t0 = __shfl_xor(v1, 1), t1 = __shfl_xor(v0, 1);
        float t2 = __shfl_xor(v3, 1), t3 = __shfl_xor(v2, 1);
        bool b1 = (j & 1) != 0;
        float u0 = b1 ? t0 : v0;
        float u1 = b1 ? v1 : t1;
        float u2 = b1 ? t2 : v2;
        float u3 = b1 ? v3 : t3;
        // stage 2 (xor 2)
        t0 = __shfl_xor(u2, 2); t1 = __shfl_xor(u3, 2);
        t2 = __shfl_xor(u0, 2); t3 = __shfl_xor(u1, 2);
        bool b2 = (j & 2) != 0;
        float g0 = b2 ? t0 : u0;   // i
        float g1 = b2 ? t1 : u1;   // f
        float g2 = b2 ? u2 : t2;   // g
        float g3 = b2 ? u3 : t3;   // o
        // wait: r=2,3 selects — sel=((j^r)&2): r=2: !(j&2)→ take t when (j&2)==0
        // (handled above: g2/g3 swap roles vs g0/g1)

        const int row = row0 + wm + m * 16 + q * 4 + j;
        const int ghc = ((n0 + wn) >> 2) + n * 4 + hcl;
        const float4 b4 = *(const float4*)&bsumv[n0 + wn + n * 16 + hcl * 4];
        float gi = g0 + b4.x, gf = g1 + b4.y, gg = g2 + b4.z, go = g3 + b4.w;

        const int cidx = row * 512 + ghc;
        float c_old = cbuf[cidx];
        float is = sigmoid_fast(gi);
        float fs = sigmoid_fast(gf);
        float os = sigmoid_fast(go);
        float gt = tanh_fast(gg);
        float cn = fs * c_old + is * gt;
        float hn = os * tanh_fast(cn);
        cbuf[cidx] = cn;
        u16 hh = f2h(hn);
        const size_t ab = (size_t)row * 1024;
        if (!IS_L1) {
            hdst[ab + ghc] = hh;                       // h0(t) -> X-slot of A1[cur]
        } else {
            hdst[ab + 512 + ghc] = hh;                 // h1(t) -> h-slot of A1[nxt]
            float h0v = h2f(h0src[ab + ghc]);
            float hs = h0v + hn;                       // hsum(t)
            hsumdst[ab + ghc] = f2h(hs);               // -> X-slot of A0[nxt]
            seqdst[(size_t)row * 512 + ghc] = f2h(hs); // seq output
        }
    }
}

// ------------------------------------------------------------------- MLP -----
template <int RELU, int FINAL>
__global__ __launch_bounds__(256) void mlp_gemm(
    const u16* __restrict__ A, const u16* __restrict__ Bw, const float* __restrict__ bias,
    u16* __restrict__ yh, float* __restrict__ yf32)
{
    __shared__ char smem[36864];
    u16* sA = (u16*)smem;             // [64][72]
    u16* sB = (u16*)(smem + 9216);    // [128][72]

    const int tid = threadIdx.x;
    const int lane = tid & 63, wid = tid >> 6;
    const int row0 = blockIdx.y * 64;
    const int n0 = blockIdx.x * 128;
    const int wn = wid * 32;
    const int fm = lane & 15;
    const int fkbase = (lane >> 4) * 8;

    f32x4 acc[4][2];
#pragma unroll
    for (int m = 0; m < 4; ++m) { acc[m][0] = (f32x4)0.f; acc[m][1] = (f32x4)0.f; }

    for (int kk = 0; kk < 8; ++kk) {
        const int k0 = kk * 64;
        __syncthreads();
#pragma unroll
        for (int r = 0; r < 2; ++r) {
            int c = tid + r * 256;
            int row = c >> 3, cc = (c & 7) * 8;
            *(f16x8*)&sA[row * 72 + cc] = *(const f16x8*)&A[(size_t)(row0 + row) * 512 + k0 + cc];
        }
#pragma unroll
        for (int r = 0; r < 4; ++r) {
            int c = tid + r * 256;
            int row = c >> 3, cc = (c & 7) * 8;
            *(f16x8*)&sB[row * 72 + cc] = *(const f16x8*)&Bw[(size_t)(n0 + row) * 512 + k0 + cc];
        }
        __syncthreads();
#pragma unroll
        for (int kf = 0; kf < 2; ++kf) {
            const int kb = kf * 32 + fkbase;
            f16x8 b0 = *(const f16x8*)&sB[(wn + fm) * 72 + kb];
            f16x8 b1 = *(const f16x8*)&sB[(wn + 16 + fm) * 72 + kb];
#pragma unroll
            for (int m = 0; m < 4; ++m) {
                f16x8 ah = *(const f16x8*)&sA[(m * 16 + fm) * 72 + kb];
                acc[m][0] = __builtin_amdgcn_mfma_f32_16x16x32_f16(ah, b0, acc[m][0], 0, 0, 0);
                acc[m][1] = __builtin_amdgcn_mfma_f32_16x16x32_f16(ah, b1, acc[m][1], 0, 0, 0);
            }
        }
    }

    __syncthreads();
    float* sG = (float*)smem;  // [64][132]
#pragma unroll
    for (int m = 0; m < 4; ++m)
#pragma unroll
        for (int n = 0; n < 2; ++n)
#pragma unroll
            for (int r = 0; r < 4; ++r) {
                int row = m * 16 + (lane >> 4) * 4 + r;
                int col = wn + n * 16 + fm;
                sG[row * 132 + col] = acc[m][n][r];
            }
    __syncthreads();

    const int row = tid >> 2;
    const int cg = (tid & 3) * 32;
    const size_t r = (size_t)row0 + row;
#pragma unroll
    for (int c = cg; c < cg + 32; c += 4) {
        float4 g = *(const float4*)&sG[row * 132 + c];
        float4 b = *(const float4*)&bias[n0 + c];
        float v0 = g.x + b.x, v1 = g.y + b.y, v2 = g.z + b.z, v3 = g.w + b.w;
        if (RELU) {
            v0 = fmaxf(v0, 0.f); v1 = fmaxf(v1, 0.f); v2 = fmaxf(v2, 0.f); v3 = fmaxf(v3, 0.f);
        }
        if (!FINAL) {
            ushort4 p;
            p.x = f2h(v0); p.y = f2h(v1); p.z = f2h(v2); p.w = f2h(v3);
            *(ushort4*)&yh[r * 512 + n0 + c] = p;
        } else {
            int tt = (int)(r >> 9), bb = (int)(r & 511);  // seq row r = t*512 + b
            float4 o; o.x = v0; o.y = v1; o.z = v2; o.w = v3;
            *(float4*)&yf32[((size_t)bb * 128 + tt) * 512 + n0 + c] = o;
        }
    }
}

// ---------------------------------------------------------------- launch -----
extern "C" void kernel_launch(void* const* d_in, const int* in_sizes, int n_in,
                              void* d_out, int out_size, void* d_ws, size_t ws_size,
                              hipStream_t stream) {
    const float* x    = (const float*)d_in[0];
    const float* W_ih = (const float*)d_in[1];
    const float* W_hh = (const float*)d_in[2];
    const float* b_ih = (const float*)d_in[3];
    const float* b_hh = (const float*)d_in[4];
    const float* fc1w = (const float*)d_in[5];
    const float* fc1b = (const float*)d_in[6];
    const float* fc2w = (const float*)d_in[7];
    const float* fc2b = (const float*)d_in[8];
    const float* fc3w = (const float*)d_in[9];
    const float* fc3b = (const float*)d_in[10];

    char* ws = (char*)d_ws;
    u16* Bpack = (u16*)(ws);                          // 8,388,608 B
    u16* fcw   = (u16*)(ws + 8388608);                // 1,572,864 B
    float* bsum = (float*)(ws + 9961472);             // 16,384 B
    u16* A0[2] = { (u16*)(ws + 9977856),  (u16*)(ws + 11026432) };   // 1MB each
    u16* A1[2] = { (u16*)(ws + 12075008), (u16*)(ws + 13123584) };   // 1MB each
    float* c0 = (float*)(ws + 14172160);              // 1MB
    float* c1 = (float*)(ws + 15220736);              // 1MB
    u16* seqb = (u16*)(ws + 20463616);                // 67,108,864 (reused as y2)
    // gb (LSTM-era) aliases the y1 (MLP-era) region — disjoint lifetimes.
    float* gb[2] = { (float*)(ws + 87572480), (float*)(ws + 87572480 + 4194304) };
    u16* y1   = (u16*)(ws + 87572480);                // 67,108,864
    float* out = (float*)d_out;

    prepack<<<dim3(512), dim3(256), 0, stream>>>(W_ih, W_hh, b_ih, b_hh, fc1w, fc2w, fc3w,
                                                 Bpack, bsum, fcw);
    initbufs<<<dim3(512), dim3(256), 0, stream>>>(x, A0[0], A1[0], c0, c1, gb[0]);

    const int LSTR = 2048 * 1024;
    for (int s = 0; s < 256; ++s) {
        int t = s >> 1, layer = s & 1, cur = t & 1, nxt = cur ^ 1;
        float* gR = gb[s & 1];
        float* gW = gb[(s + 1) & 1];
        if (!layer) {
            // completion: gates0(t) = gR + hsum(t-1)@Wih0 -> h0(t) into A1[cur] X-slot
            // partial:    gW = h1(t-1)@Whh1   (h1 from A1[cur] h-slot, W = layer1 k[512:1024))
            lstm_phase<0><<<dim3(512), dim3(256), 0, stream>>>(
                A0[cur], A1[cur], 512, Bpack, Bpack + LSTR + 512,
                gR, gW, bsum, c0,
                A1[cur], nullptr, nullptr, nullptr);
        } else {
            // completion: gates1(t) = gR + h0(t)@Wih1 -> h1(t) into A1[nxt] h-slot, hsum -> A0[nxt]
            // partial:    gW = h0(t)@Whh0     (h0 from A1[cur] X-slot, W = layer0 k[512:1024))
            lstm_phase<1><<<dim3(512), dim3(256), 0, stream>>>(
                A1[cur], A1[cur], 0, Bpack + LSTR, Bpack + 512,
                gR, gW, bsum + 2048, c1,
                A1[nxt], A1[cur], A0[nxt], seqb + (size_t)t * 262144);
        }
    }

    mlp_gemm<1, 0><<<dim3(4, 1024), dim3(256), 0, stream>>>(seqb, fcw, fc1b, y1, nullptr);
    mlp_gemm<1, 0><<<dim3(4, 1024), dim3(256), 0, stream>>>(y1, fcw + 512 * 512, fc2b, seqb, nullptr);
    mlp_gemm<0, 1><<<dim3(4, 1024), dim3(256), 0, stream>>>(seqb, fcw + 2 * 512 * 512, fc3b, nullptr, out);
}

// Round 8
// 2247.291 us; speedup vs baseline: 1.5093x; 1.5093x over previous
//
#include <hip/hip_runtime.h>
#include <cstdint>
#include <cstddef>

// DecoderLSTM: 2-layer LSTM (B=512,H=512,T=128) + 3-layer MLP head.
// fp16 datapath, fp32 accum + fp32 cell state. K-split pipelining (round 5):
// gates_s = X_s@Wx + H_s@Wh; H-half computed one dispatch early by 256 partial
// blocks while 256 completion blocks finish the current step (512 blocks, 2/CU).
// Round 8: W-operand via PACKED fragment-order layout -> fully-coalesced 1KB
// global loads straight to VGPR (W off the LDS pipe; round 7's strided version
// regressed). A stays on swizzled gl_lds staging. Shuffle-transpose epilogue
// (proven round 7) replaces the sG LDS roundtrip.

using u16 = unsigned short;
typedef __attribute__((ext_vector_type(8))) _Float16 f16x8;
typedef __attribute__((ext_vector_type(4))) float f32x4;

__device__ __forceinline__ u16 f2h(float f) {
    union { _Float16 h; u16 u; } v; v.h = (_Float16)f; return v.u;
}
__device__ __forceinline__ float h2f(u16 u) {
    union { u16 u; _Float16 h; } v; v.u = u; return (float)v.h;
}
__device__ __forceinline__ float tanh_fast(float v) {
    float a = fabsf(v);
    float t = __expf(-2.f * a);
    float r = (1.f - t) / (1.f + t);
    return copysignf(r, v);
}
__device__ __forceinline__ float sigmoid_fast(float v) {
    return 1.f / (1.f + __expf(-v));
}

__device__ __forceinline__ void gl_lds16(const u16* g, char* l) {
    __builtin_amdgcn_global_load_lds((const __attribute__((address_space(1))) char*)(const char*)g,
                                     (__attribute__((address_space(3))) char*)l, 16, 0, 0);
}

// Swizzled LDS read: tile [64 rows][64 f16] linear (128B rows = 8 x 16B units),
// unit u' holds global col-unit u'^(row&7). Involution applied to global src on
// stage and to the read index here (both sides, rule #21).
__device__ __forceinline__ f16x8 lds_read_sw(const u16* tile, int row, int cu) {
    int unit = (row << 3) | (cu ^ (row & 7));
    return *(const f16x8*)&tile[unit << 3];
}

// ---------------------------------------------------------------- prepack ----
// Packed LSTM weights: Wpk[l][half(ih,hh)][nb 32][ch 8][wn 2][nf 2][kf 2][lane 64][e 8]
//   value = W_{ih|hh}[l][ n=(np&3)*512+(np>>2) ][ k = ch*64 + kf*32 + (lane>>4)*8 + e ]
//   with np = nb*64 + wn*32 + nf*16 + (lane&15)   (np = hcol*4 + gate, gates i,f,g,o)
// One wave's (nb,ch,wn,nf,kf) fragment = 1KB contiguous -> one coalesced dwordx4 burst.
__global__ __launch_bounds__(256) void prepack(
    const float* __restrict__ W_ih, const float* __restrict__ W_hh,
    const float* __restrict__ b_ih, const float* __restrict__ b_hh,
    const float* __restrict__ fc1w, const float* __restrict__ fc2w, const float* __restrict__ fc3w,
    u16* __restrict__ Wpk, float* __restrict__ bsumv, u16* __restrict__ fcw)
{
    int stride = gridDim.x * blockDim.x;
    int tid0 = blockIdx.x * blockDim.x + threadIdx.x;
    for (int idx = tid0; idx < 4194304; idx += stride) {
        int e    = idx & 7;
        int lane = (idx >> 3) & 63;
        int kf   = (idx >> 9) & 1;
        int nf   = (idx >> 10) & 1;
        int wn   = (idx >> 11) & 1;
        int ch   = (idx >> 12) & 7;
        int nb   = (idx >> 15) & 31;
        int half = (idx >> 20) & 1;
        int l    = (idx >> 21) & 1;
        int np = nb * 64 + wn * 32 + nf * 16 + (lane & 15);
        int k  = ch * 64 + kf * 32 + ((lane >> 4) << 3) + e;
        int n  = (np & 3) * 512 + (np >> 2);
        const float* W = half ? W_hh : W_ih;
        Wpk[idx] = f2h(W[((size_t)l * 2048 + n) * 512 + k]);
    }
    for (int idx = tid0; idx < 2 * 2048; idx += stride) {
        int l = idx >> 11;
        int np = idx & 2047;
        int n = (np & 3) * 512 + (np >> 2);
        bsumv[idx] = b_ih[l * 2048 + n] + b_hh[l * 2048 + n];
    }
    for (int idx = tid0; idx < 3 * 512 * 512; idx += stride) {
        const float* w = idx < 262144 ? fc1w : (idx < 524288 ? fc2w : fc3w);
        fcw[idx] = f2h(w[idx & 262143]);
    }
}

// A buffers: [512][1024] f16: cols [0:512) = X (x / hsum / h0-as-X), [512:1024) = h
__global__ __launch_bounds__(256) void initbufs(
    const float* __restrict__ x, u16* __restrict__ A0_0, u16* __restrict__ A1_0,
    float* __restrict__ c0, float* __restrict__ c1, float* __restrict__ gb0)
{
    int stride = gridDim.x * blockDim.x;
    int tid0 = blockIdx.x * blockDim.x + threadIdx.x;
    for (int idx = tid0; idx < 512 * 512; idx += stride) {
        int row = idx >> 9, col = idx & 511;
        size_t b = (size_t)row * 1024;
        A0_0[b + col] = f2h(x[idx]);
        A1_0[b + 512 + col] = 0;     // h1(-1) = 0
        c0[idx] = 0.f;
        c1[idx] = 0.f;
    }
    for (int idx = tid0; idx < 1048576; idx += stride) gb0[idx] = 0.f;  // H-half of step 0
}

// --------------------------------------------------------------- lstm phase --
// 512 blocks x 256 thr (2/CU). Blocks 0..255: completion (gates = gbufR + X@W_x,
// epilogue). Blocks 256..511: partial for NEXT sub-step (gbufW = H@W_h).
// Per role: 64 rows x 64 n'-cols, K=512 in 8 fully-unrolled chunks of 64.
// A staged via swizzled gl_lds (3 bufs x 8KB); W: 4 coalesced 1KB bursts/chunk
// from packed layout into a 2-deep register dbuf, issued one chunk ahead,
// BEFORE the barrier (no LDS hazard). vmcnt(10) awaits only the A-stage;
// compiler's register-dep waitcnt covers W.
template <int IS_L1>
__global__ __launch_bounds__(256) void lstm_phase(
    const u16* __restrict__ Ax, const u16* __restrict__ Ah, int hoffH,
    const u16* __restrict__ Wc, const u16* __restrict__ Wp,
    const float* __restrict__ gbufR, float* __restrict__ gbufW,
    const float* __restrict__ bsumv, float* __restrict__ cbuf,
    u16* __restrict__ hdst, const u16* __restrict__ h0src,
    u16* __restrict__ hsumdst, u16* __restrict__ seqdst)
{
    __shared__ char smem[24576];   // 3 bufs x 8KB (A only)

    const int id = blockIdx.x;
    const bool isPartial = id >= 256;
    const int rid = id & 255;
    const int xcd = rid & 7, slot = rid >> 3;
    const int nb = xcd * 4 + (slot & 3);   // 0..31
    const int rg = slot >> 2;              // 0..7
    const int n0 = nb * 64;
    const int row0 = rg * 64;
    const int tile = rg * 32 + nb;

    const u16* Abase = isPartial ? Ah : Ax;
    const int xoff = isPartial ? hoffH : 0;
    const u16* Wbase = isPartial ? Wp : Wc;

    const int tid = threadIdx.x;
    const int lane = tid & 63, wid = tid >> 6;
    const int wm = (wid >> 1) * 32, wn = (wid & 1) * 32;
    const int fm = lane & 15, q = lane >> 4;

    // A staging: wave w stages 16B-units [w*128, w*128+128); global src pre-swizzled
    const int s0 = wid * 128 + lane, s1 = s0 + 64;
    const int r0s = s0 >> 3, c0s = ((s0 & 7) ^ (r0s & 7)) << 3;
    const int r1s = s1 >> 3, c1s = ((s1 & 7) ^ (r1s & 7)) << 3;
    const size_t aO0 = (size_t)(row0 + r0s) * 1024 + xoff + c0s;
    const size_t aO1 = (size_t)(row0 + r1s) * 1024 + xoff + c1s;
    const int d0 = wid * 2048, d1 = d0 + 1024;

    // W packed base for this wave: [nb][ch][wn][nf][kf][lane][8]
    const u16* pwv = Wbase + (size_t)nb * 32768 + (wid & 1) * 2048 + lane * 8;

    f32x4 acc[2][2];
    acc[0][0] = (f32x4)0.f; acc[0][1] = (f32x4)0.f;
    acc[1][0] = (f32x4)0.f; acc[1][1] = (f32x4)0.f;

    auto stage = [&](char* buf, int k0) {
        gl_lds16(Abase + aO0 + k0, buf + d0);
        gl_lds16(Abase + aO1 + k0, buf + d1);
    };

    char* bufp[3] = { smem, smem + 8192, smem + 16384 };

    // W register double-buffer: w0=(nf0,kf0) w1=(nf0,kf1) w2=(nf1,kf0) w3=(nf1,kf1)
    f16x8 w0[2], w1[2], w2[2], w3[2];

    // prologue: A chunks 0,1 staged; W chunk 0 loaded
    stage(bufp[0], 0);
    stage(bufp[1], 64);
    w0[0] = *(const f16x8*)(pwv + 0);
    w1[0] = *(const f16x8*)(pwv + 512);
    w2[0] = *(const f16x8*)(pwv + 1024);
    w3[0] = *(const f16x8*)(pwv + 1536);

#pragma unroll
    for (int c = 0; c < 8; ++c) {
        // issue next chunk's W (register slot consumed last iteration; no LDS hazard)
        if (c + 1 < 8) {
            const u16* pc = pwv + (c + 1) * 4096;
            const int p = (c + 1) & 1;
            w0[p] = *(const f16x8*)(pc + 0);
            w1[p] = *(const f16x8*)(pc + 512);
            w2[p] = *(const f16x8*)(pc + 1024);
            w3[p] = *(const f16x8*)(pc + 1536);
        }
        // await only A(c): in-flight allowed = {W(c):4, A(c+1):2, W(c+1):4} = 10
        if (c < 7) asm volatile("s_waitcnt vmcnt(10)" ::: "memory");
        else       asm volatile("s_waitcnt vmcnt(4)" ::: "memory");
        __builtin_amdgcn_s_barrier();
        if (c + 2 < 8) stage(bufp[(c + 2) % 3], (c + 2) * 64);
        __builtin_amdgcn_sched_barrier(0);

        const u16* sA = (const u16*)bufp[c % 3];
        const int p = c & 1;

        f16x8 a00 = lds_read_sw(sA, wm + fm, q);          // m0, k-half 0
        f16x8 a10 = lds_read_sw(sA, wm + 16 + fm, q);     // m1, k-half 0
        f16x8 a01 = lds_read_sw(sA, wm + fm, 4 + q);      // m0, k-half 1
        f16x8 a11 = lds_read_sw(sA, wm + 16 + fm, 4 + q); // m1, k-half 1

        acc[0][0] = __builtin_amdgcn_mfma_f32_16x16x32_f16(a00, w0[p], acc[0][0], 0, 0, 0);
        acc[0][1] = __builtin_amdgcn_mfma_f32_16x16x32_f16(a00, w2[p], acc[0][1], 0, 0, 0);
        acc[1][0] = __builtin_amdgcn_mfma_f32_16x16x32_f16(a10, w0[p], acc[1][0], 0, 0, 0);
        acc[1][1] = __builtin_amdgcn_mfma_f32_16x16x32_f16(a10, w2[p], acc[1][1], 0, 0, 0);
        acc[0][0] = __builtin_amdgcn_mfma_f32_16x16x32_f16(a01, w1[p], acc[0][0], 0, 0, 0);
        acc[0][1] = __builtin_amdgcn_mfma_f32_16x16x32_f16(a01, w3[p], acc[0][1], 0, 0, 0);
        acc[1][0] = __builtin_amdgcn_mfma_f32_16x16x32_f16(a11, w1[p], acc[1][0], 0, 0, 0);
        acc[1][1] = __builtin_amdgcn_mfma_f32_16x16x32_f16(a11, w3[p], acc[1][1], 0, 0, 0);
    }

    // ---------------- partial role: dump fragments to gbufW, done --------------
    if (isPartial) {
        float* dst = gbufW + (size_t)tile * 4096 + wid * 1024 + lane * 4;
        *(f32x4*)(dst +   0) = acc[0][0];
        *(f32x4*)(dst + 256) = acc[0][1];
        *(f32x4*)(dst + 512) = acc[1][0];
        *(f32x4*)(dst + 768) = acc[1][1];
        return;
    }

    // ---------------- completion role: add partial, LSTM epilogue --------------
    {
        const float* src = gbufR + (size_t)tile * 4096 + wid * 1024 + lane * 4;
        acc[0][0] += *(const f32x4*)(src +   0);
        acc[0][1] += *(const f32x4*)(src + 256);
        acc[1][0] += *(const f32x4*)(src + 512);
        acc[1][1] += *(const f32x4*)(src + 768);
    }

    // In-register gate regroup (proven round 7): 4x4 transpose over (lane-quad j,
    // reg r) per fragment. After transpose, lane (q, fm=4*hcl+j) holds gates
    // i,f,g,o of cell (row = wm + m*16 + q*4 + j, hc = (n0+wn)/4 + n*4 + hcl).
    const int j = fm & 3;
    const int hcl = fm >> 2;
#pragma unroll
    for (int m = 0; m < 2; ++m)
#pragma unroll
    for (int n = 0; n < 2; ++n) {
        float v0 = acc[m][n][0], v1 = acc[m][n][1], v2 = acc[m][n][2], v3 = acc[m][n][3];
        float t0 = __shfl_xor(v1, 1), t1 = __shfl_xor(v0, 1);
        float t2 = __shfl_xor(v3, 1), t3 = __shfl_xor(v2, 1);
        bool b1 = (j & 1) != 0;
        float u0 = b1 ? t0 : v0;
        float u1 = b1 ? v1 : t1;
        float u2 = b1 ? t2 : v2;
        float u3 = b1 ? v3 : t3;
        t0 = __shfl_xor(u2, 2); t1 = __shfl_xor(u3, 2);
        t2 = __shfl_xor(u0, 2); t3 = __shfl_xor(u1, 2);
        bool b2 = (j & 2) != 0;
        float g0 = b2 ? t0 : u0;   // i
        float g1 = b2 ? t1 : u1;   // f
        float g2 = b2 ? u2 : t2;   // g
        float g3 = b2 ? u3 : t3;   // o

        const int row = row0 + wm + m * 16 + q * 4 + j;
        const int ghc = ((n0 + wn) >> 2) + n * 4 + hcl;
        const float4 b4 = *(const float4*)&bsumv[n0 + wn + n * 16 + hcl * 4];
        float gi = g0 + b4.x, gf = g1 + b4.y, gg = g2 + b4.z, go = g3 + b4.w;

        const int cidx = row * 512 + ghc;
        float c_old = cbuf[cidx];
        float is = sigmoid_fast(gi);
        float fs = sigmoid_fast(gf);
        float os = sigmoid_fast(go);
        float gt = tanh_fast(gg);
        float cn = fs * c_old + is * gt;
        float hn = os * tanh_fast(cn);
        cbuf[cidx] = cn;
        u16 hh = f2h(hn);
        const size_t ab = (size_t)row * 1024;
        if (!IS_L1) {
            hdst[ab + ghc] = hh;                       // h0(t) -> X-slot of A1[cur]
        } else {
            hdst[ab + 512 + ghc] = hh;                 // h1(t) -> h-slot of A1[nxt]
            float h0v = h2f(h0src[ab + ghc]);
            float hs = h0v + hn;                       // hsum(t)
            hsumdst[ab + ghc] = f2h(hs);               // -> X-slot of A0[nxt]
            seqdst[(size_t)row * 512 + ghc] = f2h(hs); // seq output
        }
    }
}

// ------------------------------------------------------------------- MLP -----
template <int RELU, int FINAL>
__global__ __launch_bounds__(256) void mlp_gemm(
    const u16* __restrict__ A, const u16* __restrict__ Bw, const float* __restrict__ bias,
    u16* __restrict__ yh, float* __restrict__ yf32)
{
    __shared__ char smem[36864];
    u16* sA = (u16*)smem;             // [64][72]
    u16* sB = (u16*)(smem + 9216);    // [128][72]

    const int tid = threadIdx.x;
    const int lane = tid & 63, wid = tid >> 6;
    const int row0 = blockIdx.y * 64;
    const int n0 = blockIdx.x * 128;
    const int wn = wid * 32;
    const int fm = lane & 15;
    const int fkbase = (lane >> 4) * 8;

    f32x4 acc[4][2];
#pragma unroll
    for (int m = 0; m < 4; ++m) { acc[m][0] = (f32x4)0.f; acc[m][1] = (f32x4)0.f; }

    for (int kk = 0; kk < 8; ++kk) {
        const int k0 = kk * 64;
        __syncthreads();
#pragma unroll
        for (int r = 0; r < 2; ++r) {
            int c = tid + r * 256;
            int row = c >> 3, cc = (c & 7) * 8;
            *(f16x8*)&sA[row * 72 + cc] = *(const f16x8*)&A[(size_t)(row0 + row) * 512 + k0 + cc];
        }
#pragma unroll
        for (int r = 0; r < 4; ++r) {
            int c = tid + r * 256;
            int row = c >> 3, cc = (c & 7) * 8;
            *(f16x8*)&sB[row * 72 + cc] = *(const f16x8*)&Bw[(size_t)(n0 + row) * 512 + k0 + cc];
        }
        __syncthreads();
#pragma unroll
        for (int kf = 0; kf < 2; ++kf) {
            const int kb = kf * 32 + fkbase;
            f16x8 b0 = *(const f16x8*)&sB[(wn + fm) * 72 + kb];
            f16x8 b1 = *(const f16x8*)&sB[(wn + 16 + fm) * 72 + kb];
#pragma unroll
            for (int m = 0; m < 4; ++m) {
                f16x8 ah = *(const f16x8*)&sA[(m * 16 + fm) * 72 + kb];
                acc[m][0] = __builtin_amdgcn_mfma_f32_16x16x32_f16(ah, b0, acc[m][0], 0, 0, 0);
                acc[m][1] = __builtin_amdgcn_mfma_f32_16x16x32_f16(ah, b1, acc[m][1], 0, 0, 0);
            }
        }
    }

    __syncthreads();
    float* sG = (float*)smem;  // [64][132]
#pragma unroll
    for (int m = 0; m < 4; ++m)
#pragma unroll
        for (int n = 0; n < 2; ++n)
#pragma unroll
            for (int r = 0; r < 4; ++r) {
                int row = m * 16 + (lane >> 4) * 4 + r;
                int col = wn + n * 16 + fm;
                sG[row * 132 + col] = acc[m][n][r];
            }
    __syncthreads();

    const int row = tid >> 2;
    const int cg = (tid & 3) * 32;
    const size_t r = (size_t)row0 + row;
#pragma unroll
    for (int c = cg; c < cg + 32; c += 4) {
        float4 g = *(const float4*)&sG[row * 132 + c];
        float4 b = *(const float4*)&bias[n0 + c];
        float v0 = g.x + b.x, v1 = g.y + b.y, v2 = g.z + b.z, v3 = g.w + b.w;
        if (RELU) {
            v0 = fmaxf(v0, 0.f); v1 = fmaxf(v1, 0.f); v2 = fmaxf(v2, 0.f); v3 = fmaxf(v3, 0.f);
        }
        if (!FINAL) {
            ushort4 p;
            p.x = f2h(v0); p.y = f2h(v1); p.z = f2h(v2); p.w = f2h(v3);
            *(ushort4*)&yh[r * 512 + n0 + c] = p;
        } else {
            int tt = (int)(r >> 9), bb = (int)(r & 511);  // seq row r = t*512 + b
            float4 o; o.x = v0; o.y = v1; o.z = v2; o.w = v3;
            *(float4*)&yf32[((size_t)bb * 128 + tt) * 512 + n0 + c] = o;
        }
    }
}

// ---------------------------------------------------------------- launch -----
extern "C" void kernel_launch(void* const* d_in, const int* in_sizes, int n_in,
                              void* d_out, int out_size, void* d_ws, size_t ws_size,
                              hipStream_t stream) {
    const float* x    = (const float*)d_in[0];
    const float* W_ih = (const float*)d_in[1];
    const float* W_hh = (const float*)d_in[2];
    const float* b_ih = (const float*)d_in[3];
    const float* b_hh = (const float*)d_in[4];
    const float* fc1w = (const float*)d_in[5];
    const float* fc1b = (const float*)d_in[6];
    const float* fc2w = (const float*)d_in[7];
    const float* fc2b = (const float*)d_in[8];
    const float* fc3w = (const float*)d_in[9];
    const float* fc3b = (const float*)d_in[10];

    char* ws = (char*)d_ws;
    u16* Wpk   = (u16*)(ws);                          // 8,388,608 B packed LSTM W
    u16* fcw   = (u16*)(ws + 8388608);                // 1,572,864 B
    float* bsum = (float*)(ws + 9961472);             // 16,384 B
    u16* A0[2] = { (u16*)(ws + 9977856),  (u16*)(ws + 11026432) };   // 1MB each
    u16* A1[2] = { (u16*)(ws + 12075008), (u16*)(ws + 13123584) };   // 1MB each
    float* c0 = (float*)(ws + 14172160);              // 1MB
    float* c1 = (float*)(ws + 15220736);              // 1MB
    u16* seqb = (u16*)(ws + 20463616);                // 67,108,864 (reused as y2)
    // gb (LSTM-era) aliases the y1 (MLP-era) region — disjoint lifetimes.
    float* gb[2] = { (float*)(ws + 87572480), (float*)(ws + 87572480 + 4194304) };
    u16* y1   = (u16*)(ws + 87572480);                // 67,108,864
    float* out = (float*)d_out;

    prepack<<<dim3(512), dim3(256), 0, stream>>>(W_ih, W_hh, b_ih, b_hh, fc1w, fc2w, fc3w,
                                                 Wpk, bsum, fcw);
    initbufs<<<dim3(512), dim3(256), 0, stream>>>(x, A0[0], A1[0], c0, c1, gb[0]);

    // Packed-W section bases (f16 elems): [l][half] each 1,048,576 elems (2MB)
    u16* W0ih = Wpk;                 // l0, W_ih
    u16* W0hh = Wpk + 1048576;       // l0, W_hh
    u16* W1ih = Wpk + 2097152;       // l1, W_ih
    u16* W1hh = Wpk + 3145728;       // l1, W_hh

    for (int s = 0; s < 256; ++s) {
        int t = s >> 1, layer = s & 1, cur = t & 1, nxt = cur ^ 1;
        float* gR = gb[s & 1];
        float* gW = gb[(s + 1) & 1];
        if (!layer) {
            // completion: gates0(t) = gR + hsum(t-1)@Wih0 -> h0(t) into A1[cur] X-slot
            // partial:    gW = h1(t-1)@Whh1   (h1 from A1[cur] h-slot)
            lstm_phase<0><<<dim3(512), dim3(256), 0, stream>>>(
                A0[cur], A1[cur], 512, W0ih, W1hh,
                gR, gW, bsum, c0,
                A1[cur], nullptr, nullptr, nullptr);
        } else {
            // completion: gates1(t) = gR + h0(t)@Wih1 -> h1(t) into A1[nxt] h-slot, hsum -> A0[nxt]
            // partial:    gW = h0(t)@Whh0     (h0 from A1[cur] X-slot)
            lstm_phase<1><<<dim3(512), dim3(256), 0, stream>>>(
                A1[cur], A1[cur], 0, W1ih, W0hh,
                gR, gW, bsum + 2048, c1,
                A1[nxt], A1[cur], A0[nxt], seqb + (size_t)t * 262144);
        }
    }

    mlp_gemm<1, 0><<<dim3(4, 1024), dim3(256), 0, stream>>>(seqb, fcw, fc1b, y1, nullptr);
    mlp_gemm<1, 0><<<dim3(4, 1024), dim3(256), 0, stream>>>(y1, fcw + 512 * 512, fc2b, seqb, nullptr);
    mlp_gemm<0, 1><<<dim3(4, 1024), dim3(256), 0, stream>>>(seqb, fcw + 2 * 512 * 512, fc3b, nullptr, out);
}

// Round 9
// 2096.781 us; speedup vs baseline: 1.6177x; 1.0718x over previous
//
#include <hip/hip_runtime.h>
#include <cstdint>
#include <cstddef>

// DecoderLSTM: 2-layer LSTM (B=512,H=512,T=128) + 3-layer MLP head.
// fp16 datapath, fp32 accum + fp32 cell state. K-split pipelining (round 5):
// gates_s = X_s@Wx + H_s@Wh; H-half computed one dispatch early by 256 partial
// blocks while 256 completion blocks finish the current step (512 blocks, 2/CU).
// Round 9: round-6 skeleton (A AND W both via swizzled gl_lds — W-direct-to-VGPR
// regressed in r7/r8: per-wave loads duplicate W vs LDS sharing) + the
// shuffle-transpose epilogue proven in r7/r8 (no sG LDS roundtrip, no epilogue
// barriers).

using u16 = unsigned short;
typedef __attribute__((ext_vector_type(8))) _Float16 f16x8;
typedef __attribute__((ext_vector_type(4))) float f32x4;

__device__ __forceinline__ u16 f2h(float f) {
    union { _Float16 h; u16 u; } v; v.h = (_Float16)f; return v.u;
}
__device__ __forceinline__ float h2f(u16 u) {
    union { u16 u; _Float16 h; } v; v.u = u; return (float)v.h;
}
__device__ __forceinline__ float tanh_fast(float v) {
    float a = fabsf(v);
    float t = __expf(-2.f * a);
    float r = (1.f - t) / (1.f + t);
    return copysignf(r, v);
}
__device__ __forceinline__ float sigmoid_fast(float v) {
    return 1.f / (1.f + __expf(-v));
}

__device__ __forceinline__ void gl_lds16(const u16* g, char* l) {
    __builtin_amdgcn_global_load_lds((const __attribute__((address_space(1))) char*)(const char*)g,
                                     (__attribute__((address_space(3))) char*)l, 16, 0, 0);
}

// Swizzled LDS read: tile [64 rows][64 f16] linear (128B rows = 8 x 16B units),
// unit u' holds global col-unit u'^(row&7). Involution applied to global src on
// stage and to the read index here (both sides, rule #21).
__device__ __forceinline__ f16x8 lds_read_sw(const u16* tile, int row, int cu) {
    int unit = (row << 3) | (cu ^ (row & 7));
    return *(const f16x8*)&tile[unit << 3];
}

// ---------------------------------------------------------------- prepack ----
// Bpack[l][np][k] (f16), np = hcol*4 + gate (i,f,g,o), k: 0..511 = W_ih, 512..1023 = W_hh
__global__ __launch_bounds__(256) void prepack(
    const float* __restrict__ W_ih, const float* __restrict__ W_hh,
    const float* __restrict__ b_ih, const float* __restrict__ b_hh,
    const float* __restrict__ fc1w, const float* __restrict__ fc2w, const float* __restrict__ fc3w,
    u16* __restrict__ Bpack, float* __restrict__ bsumv, u16* __restrict__ fcw)
{
    int stride = gridDim.x * blockDim.x;
    int tid0 = blockIdx.x * blockDim.x + threadIdx.x;
    for (int idx = tid0; idx < 2 * 2048 * 1024; idx += stride) {
        int l = idx >> 21;
        int rem = idx & ((1 << 21) - 1);
        int np = rem >> 10;
        int k = rem & 1023;
        int n = (np & 3) * 512 + (np >> 2);
        float v = (k < 512) ? W_ih[((size_t)l * 2048 + n) * 512 + k]
                            : W_hh[((size_t)l * 2048 + n) * 512 + (k - 512)];
        Bpack[idx] = f2h(v);
    }
    for (int idx = tid0; idx < 2 * 2048; idx += stride) {
        int l = idx >> 11;
        int np = idx & 2047;
        int n = (np & 3) * 512 + (np >> 2);
        bsumv[idx] = b_ih[l * 2048 + n] + b_hh[l * 2048 + n];
    }
    for (int idx = tid0; idx < 3 * 512 * 512; idx += stride) {
        const float* w = idx < 262144 ? fc1w : (idx < 524288 ? fc2w : fc3w);
        fcw[idx] = f2h(w[idx & 262143]);
    }
}

// A buffers: [512][1024] f16: cols [0:512) = X (x / hsum / h0-as-X), [512:1024) = h
__global__ __launch_bounds__(256) void initbufs(
    const float* __restrict__ x, u16* __restrict__ A0_0, u16* __restrict__ A1_0,
    float* __restrict__ c0, float* __restrict__ c1, float* __restrict__ gb0)
{
    int stride = gridDim.x * blockDim.x;
    int tid0 = blockIdx.x * blockDim.x + threadIdx.x;
    for (int idx = tid0; idx < 512 * 512; idx += stride) {
        int row = idx >> 9, col = idx & 511;
        size_t b = (size_t)row * 1024;
        A0_0[b + col] = f2h(x[idx]);
        A1_0[b + 512 + col] = 0;     // h1(-1) = 0
        c0[idx] = 0.f;
        c1[idx] = 0.f;
    }
    for (int idx = tid0; idx < 1048576; idx += stride) gb0[idx] = 0.f;  // H-half of step 0
}

// --------------------------------------------------------------- lstm phase --
// 512 blocks x 256 thr (2/CU). Blocks 0..255: completion (gates = gbufR + X@W_x,
// epilogue). Blocks 256..511: partial for NEXT sub-step (gbufW = H@W_h).
// Each role: 64 rows x 64 n'-cols, K=512 in 8 chunks of 64; depth-2 vmcnt pipeline,
// 3 LDS bufs x 16KB (A 8K | W 8K) = 48KB. Epilogue: in-register shfl transpose.
template <int IS_L1>
__global__ __launch_bounds__(256) void lstm_phase(
    const u16* __restrict__ Ax, const u16* __restrict__ Ah, int hoffH,
    const u16* __restrict__ Wc, const u16* __restrict__ Wp,
    const float* __restrict__ gbufR, float* __restrict__ gbufW,
    const float* __restrict__ bsumv, float* __restrict__ cbuf,
    u16* __restrict__ hdst, const u16* __restrict__ h0src,
    u16* __restrict__ hsumdst, u16* __restrict__ seqdst)
{
    __shared__ char smem[49152];   // 3 bufs x (A 8K | W 8K)

    const int id = blockIdx.x;
    const bool isPartial = id >= 256;
    const int rid = id & 255;
    const int xcd = rid & 7, slot = rid >> 3;
    const int nb = xcd * 4 + (slot & 3);   // 0..31
    const int rg = slot >> 2;              // 0..7
    const int n0 = nb * 64;
    const int row0 = rg * 64;
    const int tile = rg * 32 + nb;

    const u16* Abase = isPartial ? Ah : Ax;
    const int xoff = isPartial ? hoffH : 0;
    const u16* Wbase = isPartial ? Wp : Wc;

    const int tid = threadIdx.x;
    const int lane = tid & 63, wid = tid >> 6;
    const int wm = (wid >> 1) * 32, wn = (wid & 1) * 32;
    const int fm = lane & 15, q = lane >> 4;

    // staging: wave w stages 16B-units [w*128, w*128+128) of each 512-unit tile
    const int s0 = wid * 128 + lane, s1 = s0 + 64;
    const int r0s = s0 >> 3, c0s = ((s0 & 7) ^ (r0s & 7)) << 3;
    const int r1s = s1 >> 3, c1s = ((s1 & 7) ^ (r1s & 7)) << 3;
    const size_t aO0 = (size_t)(row0 + r0s) * 1024 + xoff + c0s;
    const size_t aO1 = (size_t)(row0 + r1s) * 1024 + xoff + c1s;
    const size_t bO0 = (size_t)(n0 + r0s) * 1024 + c0s;
    const size_t bO1 = (size_t)(n0 + r1s) * 1024 + c1s;
    const int d0 = wid * 2048, d1 = d0 + 1024;

    f32x4 acc[2][2];
    acc[0][0] = (f32x4)0.f; acc[0][1] = (f32x4)0.f;
    acc[1][0] = (f32x4)0.f; acc[1][1] = (f32x4)0.f;

    auto stage = [&](char* buf, int k0) {
        gl_lds16(Abase + aO0 + k0, buf + d0);
        gl_lds16(Abase + aO1 + k0, buf + d1);
        gl_lds16(Wbase + bO0 + k0, buf + 8192 + d0);
        gl_lds16(Wbase + bO1 + k0, buf + 8192 + d1);
    };

    char* p0 = smem;
    char* p1 = smem + 16384;
    char* p2 = smem + 32768;

    stage(p0, 0);
    stage(p1, 64);

    for (int c = 0; c < 8; ++c) {
        if (c < 7) asm volatile("s_waitcnt vmcnt(4)" ::: "memory");
        else       asm volatile("s_waitcnt vmcnt(0)" ::: "memory");
        __builtin_amdgcn_s_barrier();
        if (c < 6) stage(p2, (c + 2) * 64);   // overwrites buf consumed at c-1
        __builtin_amdgcn_sched_barrier(0);

        const u16* sA = (const u16*)p0;
        const u16* sB = (const u16*)(p0 + 8192);

#pragma unroll
        for (int kf = 0; kf < 2; ++kf) {
            const int cu = kf * 4 + q;
            f16x8 b0 = lds_read_sw(sB, wn + fm, cu);
            f16x8 b1 = lds_read_sw(sB, wn + 16 + fm, cu);
            f16x8 a0 = lds_read_sw(sA, wm + fm, cu);
            f16x8 a1 = lds_read_sw(sA, wm + 16 + fm, cu);
            acc[0][0] = __builtin_amdgcn_mfma_f32_16x16x32_f16(a0, b0, acc[0][0], 0, 0, 0);
            acc[0][1] = __builtin_amdgcn_mfma_f32_16x16x32_f16(a0, b1, acc[0][1], 0, 0, 0);
            acc[1][0] = __builtin_amdgcn_mfma_f32_16x16x32_f16(a1, b0, acc[1][0], 0, 0, 0);
            acc[1][1] = __builtin_amdgcn_mfma_f32_16x16x32_f16(a1, b1, acc[1][1], 0, 0, 0);
        }

        char* t = p0; p0 = p1; p1 = p2; p2 = t;
    }

    // ---------------- partial role: dump fragments to gbufW, done --------------
    if (isPartial) {
        float* dst = gbufW + (size_t)tile * 4096 + wid * 1024 + lane * 4;
        *(f32x4*)(dst +   0) = acc[0][0];
        *(f32x4*)(dst + 256) = acc[0][1];
        *(f32x4*)(dst + 512) = acc[1][0];
        *(f32x4*)(dst + 768) = acc[1][1];
        return;
    }

    // ---------------- completion role: add partial, LSTM epilogue --------------
    {
        const float* src = gbufR + (size_t)tile * 4096 + wid * 1024 + lane * 4;
        acc[0][0] += *(const f32x4*)(src +   0);
        acc[0][1] += *(const f32x4*)(src + 256);
        acc[1][0] += *(const f32x4*)(src + 512);
        acc[1][1] += *(const f32x4*)(src + 768);
    }

    // In-register gate regroup (proven r7/r8): 4x4 shfl transpose over (lane-quad
    // j, reg r) per fragment. After transpose, lane (q, fm=4*hcl+j) holds gates
    // i,f,g,o of cell (row = wm + m*16 + q*4 + j, hc = (n0+wn)/4 + n*4 + hcl).
    const int j = fm & 3;
    const int hcl = fm >> 2;
#pragma unroll
    for (int m = 0; m < 2; ++m)
#pragma unroll
    for (int n = 0; n < 2; ++n) {
        float v0 = acc[m][n][0], v1 = acc[m][n][1], v2 = acc[m][n][2], v3 = acc[m][n][3];
        float t0 = __shfl_xor(v1, 1), t1 = __shfl_xor(v0, 1);
        float t2 = __shfl_xor(v3, 1), t3 = __shfl_xor(v2, 1);
        bool b1 = (j & 1) != 0;
        float u0 = b1 ? t0 : v0;
        float u1 = b1 ? v1 : t1;
        float u2 = b1 ? t2 : v2;
        float u3 = b1 ? v3 : t3;
        t0 = __shfl_xor(u2, 2); t1 = __shfl_xor(u3, 2);
        t2 = __shfl_xor(u0, 2); t3 = __shfl_xor(u1, 2);
        bool b2 = (j & 2) != 0;
        float g0 = b2 ? t0 : u0;   // i
        float g1 = b2 ? t1 : u1;   // f
        float g2 = b2 ? u2 : t2;   // g
        float g3 = b2 ? u3 : t3;   // o

        const int row = row0 + wm + m * 16 + q * 4 + j;
        const int ghc = ((n0 + wn) >> 2) + n * 4 + hcl;
        const float4 b4 = *(const float4*)&bsumv[n0 + wn + n * 16 + hcl * 4];
        float gi = g0 + b4.x, gf = g1 + b4.y, gg = g2 + b4.z, go = g3 + b4.w;

        const int cidx = row * 512 + ghc;
        float c_old = cbuf[cidx];
        float is = sigmoid_fast(gi);
        float fs = sigmoid_fast(gf);
        float os = sigmoid_fast(go);
        float gt = tanh_fast(gg);
        float cn = fs * c_old + is * gt;
        float hn = os * tanh_fast(cn);
        cbuf[cidx] = cn;
        u16 hh = f2h(hn);
        const size_t ab = (size_t)row * 1024;
        if (!IS_L1) {
            hdst[ab + ghc] = hh;                       // h0(t) -> X-slot of A1[cur]
        } else {
            hdst[ab + 512 + ghc] = hh;                 // h1(t) -> h-slot of A1[nxt]
            float h0v = h2f(h0src[ab + ghc]);
            float hs = h0v + hn;                       // hsum(t)
            hsumdst[ab + ghc] = f2h(hs);               // -> X-slot of A0[nxt]
            seqdst[(size_t)row * 512 + ghc] = f2h(hs); // seq output
        }
    }
}

// ------------------------------------------------------------------- MLP -----
template <int RELU, int FINAL>
__global__ __launch_bounds__(256) void mlp_gemm(
    const u16* __restrict__ A, const u16* __restrict__ Bw, const float* __restrict__ bias,
    u16* __restrict__ yh, float* __restrict__ yf32)
{
    __shared__ char smem[36864];
    u16* sA = (u16*)smem;             // [64][72]
    u16* sB = (u16*)(smem + 9216);    // [128][72]

    const int tid = threadIdx.x;
    const int lane = tid & 63, wid = tid >> 6;
    const int row0 = blockIdx.y * 64;
    const int n0 = blockIdx.x * 128;
    const int wn = wid * 32;
    const int fm = lane & 15;
    const int fkbase = (lane >> 4) * 8;

    f32x4 acc[4][2];
#pragma unroll
    for (int m = 0; m < 4; ++m) { acc[m][0] = (f32x4)0.f; acc[m][1] = (f32x4)0.f; }

    for (int kk = 0; kk < 8; ++kk) {
        const int k0 = kk * 64;
        __syncthreads();
#pragma unroll
        for (int r = 0; r < 2; ++r) {
            int c = tid + r * 256;
            int row = c >> 3, cc = (c & 7) * 8;
            *(f16x8*)&sA[row * 72 + cc] = *(const f16x8*)&A[(size_t)(row0 + row) * 512 + k0 + cc];
        }
#pragma unroll
        for (int r = 0; r < 4; ++r) {
            int c = tid + r * 256;
            int row = c >> 3, cc = (c & 7) * 8;
            *(f16x8*)&sB[row * 72 + cc] = *(const f16x8*)&Bw[(size_t)(n0 + row) * 512 + k0 + cc];
        }
        __syncthreads();
#pragma unroll
        for (int kf = 0; kf < 2; ++kf) {
            const int kb = kf * 32 + fkbase;
            f16x8 b0 = *(const f16x8*)&sB[(wn + fm) * 72 + kb];
            f16x8 b1 = *(const f16x8*)&sB[(wn + 16 + fm) * 72 + kb];
#pragma unroll
            for (int m = 0; m < 4; ++m) {
                f16x8 ah = *(const f16x8*)&sA[(m * 16 + fm) * 72 + kb];
                acc[m][0] = __builtin_amdgcn_mfma_f32_16x16x32_f16(ah, b0, acc[m][0], 0, 0, 0);
                acc[m][1] = __builtin_amdgcn_mfma_f32_16x16x32_f16(ah, b1, acc[m][1], 0, 0, 0);
            }
        }
    }

    __syncthreads();
    float* sG = (float*)smem;  // [64][132]
#pragma unroll
    for (int m = 0; m < 4; ++m)
#pragma unroll
        for (int n = 0; n < 2; ++n)
#pragma unroll
            for (int r = 0; r < 4; ++r) {
                int row = m * 16 + (lane >> 4) * 4 + r;
                int col = wn + n * 16 + fm;
                sG[row * 132 + col] = acc[m][n][r];
            }
    __syncthreads();

    const int row = tid >> 2;
    const int cg = (tid & 3) * 32;
    const size_t r = (size_t)row0 + row;
#pragma unroll
    for (int c = cg; c < cg + 32; c += 4) {
        float4 g = *(const float4*)&sG[row * 132 + c];
        float4 b = *(const float4*)&bias[n0 + c];
        float v0 = g.x + b.x, v1 = g.y + b.y, v2 = g.z + b.z, v3 = g.w + b.w;
        if (RELU) {
            v0 = fmaxf(v0, 0.f); v1 = fmaxf(v1, 0.f); v2 = fmaxf(v2, 0.f); v3 = fmaxf(v3, 0.f);
        }
        if (!FINAL) {
            ushort4 p;
            p.x = f2h(v0); p.y = f2h(v1); p.z = f2h(v2); p.w = f2h(v3);
            *(ushort4*)&yh[r * 512 + n0 + c] = p;
        } else {
            int tt = (int)(r >> 9), bb = (int)(r & 511);  // seq row r = t*512 + b
            float4 o; o.x = v0; o.y = v1; o.z = v2; o.w = v3;
            *(float4*)&yf32[((size_t)bb * 128 + tt) * 512 + n0 + c] = o;
        }
    }
}

// ---------------------------------------------------------------- launch -----
extern "C" void kernel_launch(void* const* d_in, const int* in_sizes, int n_in,
                              void* d_out, int out_size, void* d_ws, size_t ws_size,
                              hipStream_t stream) {
    const float* x    = (const float*)d_in[0];
    const float* W_ih = (const float*)d_in[1];
    const float* W_hh = (const float*)d_in[2];
    const float* b_ih = (const float*)d_in[3];
    const float* b_hh = (const float*)d_in[4];
    const float* fc1w = (const float*)d_in[5];
    const float* fc1b = (const float*)d_in[6];
    const float* fc2w = (const float*)d_in[7];
    const float* fc2b = (const float*)d_in[8];
    const float* fc3w = (const float*)d_in[9];
    const float* fc3b = (const float*)d_in[10];

    char* ws = (char*)d_ws;
    u16* Bpack = (u16*)(ws);                          // 8,388,608 B
    u16* fcw   = (u16*)(ws + 8388608);                // 1,572,864 B
    float* bsum = (float*)(ws + 9961472);             // 16,384 B
    u16* A0[2] = { (u16*)(ws + 9977856),  (u16*)(ws + 11026432) };   // 1MB each
    u16* A1[2] = { (u16*)(ws + 12075008), (u16*)(ws + 13123584) };   // 1MB each
    float* c0 = (float*)(ws + 14172160);              // 1MB
    float* c1 = (float*)(ws + 15220736);              // 1MB
    u16* seqb = (u16*)(ws + 20463616);                // 67,108,864 (reused as y2)
    // gb (LSTM-era) aliases the y1 (MLP-era) region — disjoint lifetimes.
    float* gb[2] = { (float*)(ws + 87572480), (float*)(ws + 87572480 + 4194304) };
    u16* y1   = (u16*)(ws + 87572480);                // 67,108,864
    float* out = (float*)d_out;

    prepack<<<dim3(512), dim3(256), 0, stream>>>(W_ih, W_hh, b_ih, b_hh, fc1w, fc2w, fc3w,
                                                 Bpack, bsum, fcw);
    initbufs<<<dim3(512), dim3(256), 0, stream>>>(x, A0[0], A1[0], c0, c1, gb[0]);

    const int LSTR = 2048 * 1024;
    for (int s = 0; s < 256; ++s) {
        int t = s >> 1, layer = s & 1, cur = t & 1, nxt = cur ^ 1;
        float* gR = gb[s & 1];
        float* gW = gb[(s + 1) & 1];
        if (!layer) {
            // completion: gates0(t) = gR + hsum(t-1)@Wih0 -> h0(t) into A1[cur] X-slot
            // partial:    gW = h1(t-1)@Whh1   (h1 from A1[cur] h-slot, W = layer1 k[512:1024))
            lstm_phase<0><<<dim3(512), dim3(256), 0, stream>>>(
                A0[cur], A1[cur], 512, Bpack, Bpack + LSTR + 512,
                gR, gW, bsum, c0,
                A1[cur], nullptr, nullptr, nullptr);
        } else {
            // completion: gates1(t) = gR + h0(t)@Wih1 -> h1(t) into A1[nxt] h-slot, hsum -> A0[nxt]
            // partial:    gW = h0(t)@Whh0     (h0 from A1[cur] X-slot, W = layer0 k[512:1024))
            lstm_phase<1><<<dim3(512), dim3(256), 0, stream>>>(
                A1[cur], A1[cur], 0, Bpack + LSTR, Bpack + 512,
                gR, gW, bsum + 2048, c1,
                A1[nxt], A1[cur], A0[nxt], seqb + (size_t)t * 262144);
        }
    }

    mlp_gemm<1, 0><<<dim3(4, 1024), dim3(256), 0, stream>>>(seqb, fcw, fc1b, y1, nullptr);
    mlp_gemm<1, 0><<<dim3(4, 1024), dim3(256), 0, stream>>>(y1, fcw + 512 * 512, fc2b, seqb, nullptr);
    mlp_gemm<0, 1><<<dim3(4, 1024), dim3(256), 0, stream>>>(seqb, fcw + 2 * 512 * 512, fc3b, nullptr, out);
}

// Round 11
// 2066.300 us; speedup vs baseline: 1.6415x; 1.0148x over previous
//
#include <hip/hip_runtime.h>
#include <cstdint>
#include <cstddef>

// DecoderLSTM: 2-layer LSTM (B=512,H=512,T=128) + 3-layer MLP head.
// fp16 datapath, fp32 accum + fp32 cell state. K-split pipelining (round 5):
// gates_s = X_s@Wx + H_s@Wh; H-half computed one dispatch early by 256 partial
// blocks while 256 completion blocks finish the current step (512 blocks, 2/CU).
// Round 11: BISECT of round-10's failure. LSTM = round-6 EXACT (proven 2023us:
// 3 bufs, depth-2 counted vmcnt(4), sG epilogue). MLP = gl_lds staging but with
// conservative __syncthreads()-drained double buffer (no counted vmcnt -> no
// pipelining race surface; staging latency still hides under compute).

using u16 = unsigned short;
typedef __attribute__((ext_vector_type(8))) _Float16 f16x8;
typedef __attribute__((ext_vector_type(4))) float f32x4;

__device__ __forceinline__ u16 f2h(float f) {
    union { _Float16 h; u16 u; } v; v.h = (_Float16)f; return v.u;
}
__device__ __forceinline__ float h2f(u16 u) {
    union { u16 u; _Float16 h; } v; v.u = u; return (float)v.h;
}
__device__ __forceinline__ float tanh_fast(float v) {
    float a = fabsf(v);
    float t = __expf(-2.f * a);
    float r = (1.f - t) / (1.f + t);
    return copysignf(r, v);
}
__device__ __forceinline__ float sigmoid_fast(float v) {
    return 1.f / (1.f + __expf(-v));
}

__device__ __forceinline__ void gl_lds16(const u16* g, char* l) {
    __builtin_amdgcn_global_load_lds((const __attribute__((address_space(1))) char*)(const char*)g,
                                     (__attribute__((address_space(3))) char*)l, 16, 0, 0);
}

// Swizzled LDS read: tile [rows][64 f16] linear (128B rows = 8 x 16B units),
// unit u' holds global col-unit u'^(row&7). Involution applied to global src on
// stage and to the read index here (both sides, rule #21).
__device__ __forceinline__ f16x8 lds_read_sw(const u16* tile, int row, int cu) {
    int unit = (row << 3) | (cu ^ (row & 7));
    return *(const f16x8*)&tile[unit << 3];
}

// ---------------------------------------------------------------- prepack ----
// Bpack[l][np][k] (f16), np = hcol*4 + gate (i,f,g,o), k: 0..511 = W_ih, 512..1023 = W_hh
__global__ __launch_bounds__(256) void prepack(
    const float* __restrict__ W_ih, const float* __restrict__ W_hh,
    const float* __restrict__ b_ih, const float* __restrict__ b_hh,
    const float* __restrict__ fc1w, const float* __restrict__ fc2w, const float* __restrict__ fc3w,
    u16* __restrict__ Bpack, float* __restrict__ bsumv, u16* __restrict__ fcw)
{
    int stride = gridDim.x * blockDim.x;
    int tid0 = blockIdx.x * blockDim.x + threadIdx.x;
    for (int idx = tid0; idx < 2 * 2048 * 1024; idx += stride) {
        int l = idx >> 21;
        int rem = idx & ((1 << 21) - 1);
        int np = rem >> 10;
        int k = rem & 1023;
        int n = (np & 3) * 512 + (np >> 2);
        float v = (k < 512) ? W_ih[((size_t)l * 2048 + n) * 512 + k]
                            : W_hh[((size_t)l * 2048 + n) * 512 + (k - 512)];
        Bpack[idx] = f2h(v);
    }
    for (int idx = tid0; idx < 2 * 2048; idx += stride) {
        int l = idx >> 11;
        int np = idx & 2047;
        int n = (np & 3) * 512 + (np >> 2);
        bsumv[idx] = b_ih[l * 2048 + n] + b_hh[l * 2048 + n];
    }
    for (int idx = tid0; idx < 3 * 512 * 512; idx += stride) {
        const float* w = idx < 262144 ? fc1w : (idx < 524288 ? fc2w : fc3w);
        fcw[idx] = f2h(w[idx & 262143]);
    }
}

// A buffers: [512][1024] f16: cols [0:512) = X (x / hsum / h0-as-X), [512:1024) = h
__global__ __launch_bounds__(256) void initbufs(
    const float* __restrict__ x, u16* __restrict__ A0_0, u16* __restrict__ A1_0,
    float* __restrict__ c0, float* __restrict__ c1, float* __restrict__ gb0)
{
    int stride = gridDim.x * blockDim.x;
    int tid0 = blockIdx.x * blockDim.x + threadIdx.x;
    for (int idx = tid0; idx < 512 * 512; idx += stride) {
        int row = idx >> 9, col = idx & 511;
        size_t b = (size_t)row * 1024;
        A0_0[b + col] = f2h(x[idx]);
        A1_0[b + 512 + col] = 0;     // h1(-1) = 0
        c0[idx] = 0.f;
        c1[idx] = 0.f;
    }
    for (int idx = tid0; idx < 1048576; idx += stride) gb0[idx] = 0.f;  // H-half of step 0
}

// --------------------------------------------------------------- lstm phase --
// ROUND-6 EXACT. 512 blocks x 256 thr (2/CU). Blocks 0..255: completion
// (gates = gbufR + X@W_x, epilogue). Blocks 256..511: partial (gbufW = H@W_h).
// Each role: 64 rows x 64 n'-cols, K=512 in 8 chunks of 64; depth-2 vmcnt
// pipeline, 3 LDS bufs x 16KB (A 8K | W 8K) = 48KB.
template <int IS_L1>
__global__ __launch_bounds__(256) void lstm_phase(
    const u16* __restrict__ Ax, const u16* __restrict__ Ah, int hoffH,
    const u16* __restrict__ Wc, const u16* __restrict__ Wp,
    const float* __restrict__ gbufR, float* __restrict__ gbufW,
    const float* __restrict__ bsumv, float* __restrict__ cbuf,
    u16* __restrict__ hdst, const u16* __restrict__ h0src,
    u16* __restrict__ hsumdst, u16* __restrict__ seqdst)
{
    __shared__ char smem[49152];   // 3 bufs x (A 8K | W 8K)

    const int id = blockIdx.x;
    const bool isPartial = id >= 256;
    const int rid = id & 255;
    const int xcd = rid & 7, slot = rid >> 3;
    const int nb = xcd * 4 + (slot & 3);   // 0..31
    const int rg = slot >> 2;              // 0..7
    const int n0 = nb * 64;
    const int row0 = rg * 64;
    const int tile = rg * 32 + nb;

    const u16* Abase = isPartial ? Ah : Ax;
    const int xoff = isPartial ? hoffH : 0;
    const u16* Wbase = isPartial ? Wp : Wc;

    const int tid = threadIdx.x;
    const int lane = tid & 63, wid = tid >> 6;
    const int wm = (wid >> 1) * 32, wn = (wid & 1) * 32;
    const int fm = lane & 15, q = lane >> 4;

    // staging: wave w stages 16B-units [w*128, w*128+128) of each 512-unit tile
    const int s0 = wid * 128 + lane, s1 = s0 + 64;
    const int r0s = s0 >> 3, c0s = ((s0 & 7) ^ (r0s & 7)) << 3;
    const int r1s = s1 >> 3, c1s = ((s1 & 7) ^ (r1s & 7)) << 3;
    const size_t aO0 = (size_t)(row0 + r0s) * 1024 + xoff + c0s;
    const size_t aO1 = (size_t)(row0 + r1s) * 1024 + xoff + c1s;
    const size_t bO0 = (size_t)(n0 + r0s) * 1024 + c0s;
    const size_t bO1 = (size_t)(n0 + r1s) * 1024 + c1s;
    const int d0 = wid * 2048, d1 = d0 + 1024;

    f32x4 acc[2][2];
    acc[0][0] = (f32x4)0.f; acc[0][1] = (f32x4)0.f;
    acc[1][0] = (f32x4)0.f; acc[1][1] = (f32x4)0.f;

    auto stage = [&](char* buf, int k0) {
        gl_lds16(Abase + aO0 + k0, buf + d0);
        gl_lds16(Abase + aO1 + k0, buf + d1);
        gl_lds16(Wbase + bO0 + k0, buf + 8192 + d0);
        gl_lds16(Wbase + bO1 + k0, buf + 8192 + d1);
    };

    char* p0 = smem;
    char* p1 = smem + 16384;
    char* p2 = smem + 32768;

    stage(p0, 0);
    stage(p1, 64);

    for (int c = 0; c < 8; ++c) {
        if (c < 7) asm volatile("s_waitcnt vmcnt(4)" ::: "memory");
        else       asm volatile("s_waitcnt vmcnt(0)" ::: "memory");
        __builtin_amdgcn_s_barrier();
        if (c < 6) stage(p2, (c + 2) * 64);   // overwrites buf consumed at c-1
        __builtin_amdgcn_sched_barrier(0);

        const u16* sA = (const u16*)p0;
        const u16* sB = (const u16*)(p0 + 8192);

#pragma unroll
        for (int kf = 0; kf < 2; ++kf) {
            const int cu = kf * 4 + q;
            f16x8 b0 = lds_read_sw(sB, wn + fm, cu);
            f16x8 b1 = lds_read_sw(sB, wn + 16 + fm, cu);
            f16x8 a0 = lds_read_sw(sA, wm + fm, cu);
            f16x8 a1 = lds_read_sw(sA, wm + 16 + fm, cu);
            acc[0][0] = __builtin_amdgcn_mfma_f32_16x16x32_f16(a0, b0, acc[0][0], 0, 0, 0);
            acc[0][1] = __builtin_amdgcn_mfma_f32_16x16x32_f16(a0, b1, acc[0][1], 0, 0, 0);
            acc[1][0] = __builtin_amdgcn_mfma_f32_16x16x32_f16(a1, b0, acc[1][0], 0, 0, 0);
            acc[1][1] = __builtin_amdgcn_mfma_f32_16x16x32_f16(a1, b1, acc[1][1], 0, 0, 0);
        }

        char* t = p0; p0 = p1; p1 = p2; p2 = t;
    }

    // ---------------- partial role: dump fragments to gbufW, done --------------
    if (isPartial) {
        float* dst = gbufW + (size_t)tile * 4096 + wid * 1024 + lane * 4;
        *(f32x4*)(dst +   0) = acc[0][0];
        *(f32x4*)(dst + 256) = acc[0][1];
        *(f32x4*)(dst + 512) = acc[1][0];
        *(f32x4*)(dst + 768) = acc[1][1];
        return;
    }

    // ---------------- completion role: add partial, LSTM epilogue --------------
    {
        const float* src = gbufR + (size_t)tile * 4096 + wid * 1024 + lane * 4;
        acc[0][0] += *(const f32x4*)(src +   0);
        acc[0][1] += *(const f32x4*)(src + 256);
        acc[1][0] += *(const f32x4*)(src + 512);
        acc[1][1] += *(const f32x4*)(src + 768);
    }

    __syncthreads();   // drain before reusing smem as sG
    float* sG = (float*)smem;  // [64][68]
#pragma unroll
    for (int m = 0; m < 2; ++m)
#pragma unroll
        for (int n = 0; n < 2; ++n)
#pragma unroll
            for (int r = 0; r < 4; ++r) {
                int row = wm + m * 16 + q * 4 + r;
                int col = wn + n * 16 + fm;
                sG[row * 68 + col] = acc[m][n][r];
            }
    __syncthreads();

#pragma unroll
    for (int j = 0; j < 4; ++j) {
        int cell = tid + j * 256;           // 64 rows x 16 hcols
        int row = cell >> 4, hc = cell & 15;
        const float4 g4 = *(const float4*)&sG[row * 68 + hc * 4];
        const float4 b4 = *(const float4*)&bsumv[n0 + hc * 4];
        float gi = g4.x + b4.x, gf = g4.y + b4.y, gg = g4.z + b4.z, go = g4.w + b4.w;
        int grow = row0 + row;
        int ghc = (n0 >> 2) + hc;
        int cidx = grow * 512 + ghc;
        float c_old = cbuf[cidx];
        float is = sigmoid_fast(gi);
        float fs = sigmoid_fast(gf);
        float os = sigmoid_fast(go);
        float gt = tanh_fast(gg);
        float cn = fs * c_old + is * gt;
        float hn = os * tanh_fast(cn);
        cbuf[cidx] = cn;
        u16 hh = f2h(hn);
        size_t ab = (size_t)grow * 1024;
        if (!IS_L1) {
            // h0(t) -> X-slot of A1[cur] (read by layer1 completion AND partial(s+1))
            hdst[ab + ghc] = hh;
        } else {
            // h1(t) -> h-slot of A1[nxt] (read by partial at s+2)
            hdst[ab + 512 + ghc] = hh;
            // hsum(t) = h0(t) + h1(t) -> X-slot of A0[nxt] + seq output
            float h0v = h2f(h0src[ab + ghc]);
            float hs = h0v + hn;
            hsumdst[ab + ghc] = f2h(hs);
            seqdst[(size_t)grow * 512 + ghc] = f2h(hs);
        }
    }
}

// ------------------------------------------------------------------- MLP -----
// gl_lds staging with CONSERVATIVE __syncthreads()-drained double buffer
// (m97 structure): stage(next) -> compute(current) -> __syncthreads (full
// drain + barrier). No counted vmcnt -> no pipelining race surface. Staging
// geometry identical to the verified bijective involution layout.
// 64 rows x 128 cols per block, K=512 in 8 chunks; 2 bufs x (A 8K | B 16K).
template <int RELU, int FINAL>
__global__ __launch_bounds__(256) void mlp_gemm(
    const u16* __restrict__ A, const u16* __restrict__ Bw, const float* __restrict__ bias,
    u16* __restrict__ yh, float* __restrict__ yf32)
{
    __shared__ char smem[49152];   // 2 bufs x 24KB

    const int tid = threadIdx.x;
    const int lane = tid & 63, wid = tid >> 6;
    const int row0 = blockIdx.y * 64;
    const int n0 = blockIdx.x * 128;
    const int wn = wid * 32;
    const int fm = lane & 15, q = lane >> 4;

    // A staging: 512 units; wave w stages units [w*128, w*128+128) (2 instrs)
    const int sA0 = wid * 128 + lane, sA1 = sA0 + 64;
    const int rA0 = sA0 >> 3, cA0 = ((sA0 & 7) ^ (rA0 & 7)) << 3;
    const int rA1 = sA1 >> 3, cA1 = ((sA1 & 7) ^ (rA1 & 7)) << 3;
    const size_t aO0 = (size_t)(row0 + rA0) * 512 + cA0;
    const size_t aO1 = (size_t)(row0 + rA1) * 512 + cA1;
    // B staging: 1024 units; wave w stages units [w*256, w*256+256) (4 instrs)
    const int sB0 = wid * 256 + lane;
    int rB[4], cB[4];
#pragma unroll
    for (int i = 0; i < 4; ++i) {
        int s = sB0 + i * 64;
        rB[i] = s >> 3; cB[i] = ((s & 7) ^ (rB[i] & 7)) << 3;
    }
    const size_t bO0 = (size_t)(n0 + rB[0]) * 512 + cB[0];
    const size_t bO1 = (size_t)(n0 + rB[1]) * 512 + cB[1];
    const size_t bO2 = (size_t)(n0 + rB[2]) * 512 + cB[2];
    const size_t bO3 = (size_t)(n0 + rB[3]) * 512 + cB[3];
    const int dA0 = wid * 2048, dA1 = dA0 + 1024;
    const int dB0 = 8192 + wid * 4096;

    f32x4 acc[4][2];
#pragma unroll
    for (int m = 0; m < 4; ++m) { acc[m][0] = (f32x4)0.f; acc[m][1] = (f32x4)0.f; }

    auto stage = [&](char* buf, int k0) {
        gl_lds16(A + aO0 + k0, buf + dA0);
        gl_lds16(A + aO1 + k0, buf + dA1);
        gl_lds16(Bw + bO0 + k0, buf + dB0);
        gl_lds16(Bw + bO1 + k0, buf + dB0 + 1024);
        gl_lds16(Bw + bO2 + k0, buf + dB0 + 2048);
        gl_lds16(Bw + bO3 + k0, buf + dB0 + 3072);
    };

    char* bufs[2] = { smem, smem + 24576 };

    stage(bufs[0], 0);
    __syncthreads();   // full drain: chunk 0 resident

    for (int c = 0; c < 8; ++c) {
        if (c + 1 < 8) stage(bufs[(c + 1) & 1], (c + 1) * 64);  // hides under compute

        const u16* sA = (const u16*)bufs[c & 1];
        const u16* sB = (const u16*)(bufs[c & 1] + 8192);

#pragma unroll
        for (int kf = 0; kf < 2; ++kf) {
            const int cu = kf * 4 + q;
            f16x8 b0 = lds_read_sw(sB, wn + fm, cu);
            f16x8 b1 = lds_read_sw(sB, wn + 16 + fm, cu);
#pragma unroll
            for (int m = 0; m < 4; ++m) {
                f16x8 ah = lds_read_sw(sA, m * 16 + fm, cu);
                acc[m][0] = __builtin_amdgcn_mfma_f32_16x16x32_f16(ah, b0, acc[m][0], 0, 0, 0);
                acc[m][1] = __builtin_amdgcn_mfma_f32_16x16x32_f16(ah, b1, acc[m][1], 0, 0, 0);
            }
        }

        __syncthreads();   // drains vmcnt(0)+lgkmcnt(0) then barrier: next chunk ready
    }

    float* sG = (float*)smem;  // [64][132]
#pragma unroll
    for (int m = 0; m < 4; ++m)
#pragma unroll
        for (int n = 0; n < 2; ++n)
#pragma unroll
            for (int r = 0; r < 4; ++r) {
                int row = m * 16 + q * 4 + r;
                int col = wn + n * 16 + fm;
                sG[row * 132 + col] = acc[m][n][r];
            }
    __syncthreads();

    const int row = tid >> 2;
    const int cg = (tid & 3) * 32;
    const size_t r = (size_t)row0 + row;
#pragma unroll
    for (int c = cg; c < cg + 32; c += 4) {
        float4 g = *(const float4*)&sG[row * 132 + c];
        float4 b = *(const float4*)&bias[n0 + c];
        float v0 = g.x + b.x, v1 = g.y + b.y, v2 = g.z + b.z, v3 = g.w + b.w;
        if (RELU) {
            v0 = fmaxf(v0, 0.f); v1 = fmaxf(v1, 0.f); v2 = fmaxf(v2, 0.f); v3 = fmaxf(v3, 0.f);
        }
        if (!FINAL) {
            ushort4 p;
            p.x = f2h(v0); p.y = f2h(v1); p.z = f2h(v2); p.w = f2h(v3);
            *(ushort4*)&yh[r * 512 + n0 + c] = p;
        } else {
            int tt = (int)(r >> 9), bb = (int)(r & 511);  // seq row r = t*512 + b
            float4 o; o.x = v0; o.y = v1; o.z = v2; o.w = v3;
            *(float4*)&yf32[((size_t)bb * 128 + tt) * 512 + n0 + c] = o;
        }
    }
}

// ---------------------------------------------------------------- launch -----
extern "C" void kernel_launch(void* const* d_in, const int* in_sizes, int n_in,
                              void* d_out, int out_size, void* d_ws, size_t ws_size,
                              hipStream_t stream) {
    const float* x    = (const float*)d_in[0];
    const float* W_ih = (const float*)d_in[1];
    const float* W_hh = (const float*)d_in[2];
    const float* b_ih = (const float*)d_in[3];
    const float* b_hh = (const float*)d_in[4];
    const float* fc1w = (const float*)d_in[5];
    const float* fc1b = (const float*)d_in[6];
    const float* fc2w = (const float*)d_in[7];
    const float* fc2b = (const float*)d_in[8];
    const float* fc3w = (const float*)d_in[9];
    const float* fc3b = (const float*)d_in[10];

    char* ws = (char*)d_ws;
    u16* Bpack = (u16*)(ws);                          // 8,388,608 B
    u16* fcw   = (u16*)(ws + 8388608);                // 1,572,864 B
    float* bsum = (float*)(ws + 9961472);             // 16,384 B
    u16* A0[2] = { (u16*)(ws + 9977856),  (u16*)(ws + 11026432) };   // 1MB each
    u16* A1[2] = { (u16*)(ws + 12075008), (u16*)(ws + 13123584) };   // 1MB each
    float* c0 = (float*)(ws + 14172160);              // 1MB
    float* c1 = (float*)(ws + 15220736);              // 1MB
    u16* seqb = (u16*)(ws + 20463616);                // 67,108,864 (reused as y2)
    // gb (LSTM-era) aliases the y1 (MLP-era) region — disjoint lifetimes.
    float* gb[2] = { (float*)(ws + 87572480), (float*)(ws + 87572480 + 4194304) };
    u16* y1   = (u16*)(ws + 87572480);                // 67,108,864
    float* out = (float*)d_out;

    prepack<<<dim3(512), dim3(256), 0, stream>>>(W_ih, W_hh, b_ih, b_hh, fc1w, fc2w, fc3w,
                                                 Bpack, bsum, fcw);
    initbufs<<<dim3(512), dim3(256), 0, stream>>>(x, A0[0], A1[0], c0, c1, gb[0]);

    const int LSTR = 2048 * 1024;
    for (int s = 0; s < 256; ++s) {
        int t = s >> 1, layer = s & 1, cur = t & 1, nxt = cur ^ 1;
        float* gR = gb[s & 1];
        float* gW = gb[(s + 1) & 1];
        if (!layer) {
            // completion: gates0(t) = gR + hsum(t-1)@Wih0 -> h0(t) into A1[cur] X-slot
            // partial:    gW = h1(t-1)@Whh1   (h1 from A1[cur] h-slot, W = layer1 k[512:1024))
            lstm_phase<0><<<dim3(512), dim3(256), 0, stream>>>(
                A0[cur], A1[cur], 512, Bpack, Bpack + LSTR + 512,
                gR, gW, bsum, c0,
                A1[cur], nullptr, nullptr, nullptr);
        } else {
            // completion: gates1(t) = gR + h0(t)@Wih1 -> h1(t) into A1[nxt] h-slot, hsum -> A0[nxt]
            // partial:    gW = h0(t)@Whh0     (h0 from A1[cur] X-slot, W = layer0 k[512:1024))
            lstm_phase<1><<<dim3(512), dim3(256), 0, stream>>>(
                A1[cur], A1[cur], 0, Bpack + LSTR, Bpack + 512,
                gR, gW, bsum + 2048, c1,
                A1[nxt], A1[cur], A0[nxt], seqb + (size_t)t * 262144);
        }
    }

    mlp_gemm<1, 0><<<dim3(4, 1024), dim3(256), 0, stream>>>(seqb, fcw, fc1b, y1, nullptr);
    mlp_gemm<1, 0><<<dim3(4, 1024), dim3(256), 0, stream>>>(y1, fcw + 512 * 512, fc2b, seqb, nullptr);
    mlp_gemm<0, 1><<<dim3(4, 1024), dim3(256), 0, stream>>>(seqb, fcw + 2 * 512 * 512, fc3b, nullptr, out);
}

// Round 12
// 1956.672 us; speedup vs baseline: 1.7335x; 1.0560x over previous
//
#include <hip/hip_runtime.h>
#include <cstdint>
#include <cstddef>

// DecoderLSTM: 2-layer LSTM (B=512,H=512,T=128) + 3-layer MLP head.
// fp16 datapath, fp32 accum + fp32 cell state. K-split pipelining (round 5):
// gates_s = X_s@Wx + H_s@Wh; H-half computed one dispatch early by 256 partial
// blocks while 256 completion blocks finish the current step (512 blocks, 2/CU).
// Round 12: swapped-operand MFMA (gates^T = W·X^T) — with np=4*hcol+gate weight
// packing, one lane's 4 acc regs = the 4 gates of ONE cell -> LSTM update fully
// in-register (no 34KB sG roundtrip). c relaid out [hcol][batch] (coalesced);
// h routed via 2KB LDS buffer -> coalesced output pass with r6's access quality.
// MLP = round-6 original (4096 blocks -> TLP-saturated; gl_lds gained nothing).

using u16 = unsigned short;
typedef __attribute__((ext_vector_type(8))) _Float16 f16x8;
typedef __attribute__((ext_vector_type(4))) float f32x4;

__device__ __forceinline__ u16 f2h(float f) {
    union { _Float16 h; u16 u; } v; v.h = (_Float16)f; return v.u;
}
__device__ __forceinline__ float h2f(u16 u) {
    union { u16 u; _Float16 h; } v; v.u = u; return (float)v.h;
}
__device__ __forceinline__ float tanh_fast(float v) {
    float a = fabsf(v);
    float t = __expf(-2.f * a);
    float r = (1.f - t) / (1.f + t);
    return copysignf(r, v);
}
__device__ __forceinline__ float sigmoid_fast(float v) {
    return 1.f / (1.f + __expf(-v));
}

__device__ __forceinline__ void gl_lds16(const u16* g, char* l) {
    __builtin_amdgcn_global_load_lds((const __attribute__((address_space(1))) char*)(const char*)g,
                                     (__attribute__((address_space(3))) char*)l, 16, 0, 0);
}

// Swizzled LDS read: tile [rows][64 f16] linear (128B rows = 8 x 16B units),
// unit u' holds global col-unit u'^(row&7). Involution applied to global src on
// stage and to the read index here (both sides, rule #21).
__device__ __forceinline__ f16x8 lds_read_sw(const u16* tile, int row, int cu) {
    int unit = (row << 3) | (cu ^ (row & 7));
    return *(const f16x8*)&tile[unit << 3];
}

// ---------------------------------------------------------------- prepack ----
// Bpack[l][np][k] (f16), np = hcol*4 + gate (i,f,g,o), k: 0..511 = W_ih, 512..1023 = W_hh
__global__ __launch_bounds__(256) void prepack(
    const float* __restrict__ W_ih, const float* __restrict__ W_hh,
    const float* __restrict__ b_ih, const float* __restrict__ b_hh,
    const float* __restrict__ fc1w, const float* __restrict__ fc2w, const float* __restrict__ fc3w,
    u16* __restrict__ Bpack, float* __restrict__ bsumv, u16* __restrict__ fcw)
{
    int stride = gridDim.x * blockDim.x;
    int tid0 = blockIdx.x * blockDim.x + threadIdx.x;
    for (int idx = tid0; idx < 2 * 2048 * 1024; idx += stride) {
        int l = idx >> 21;
        int rem = idx & ((1 << 21) - 1);
        int np = rem >> 10;
        int k = rem & 1023;
        int n = (np & 3) * 512 + (np >> 2);
        float v = (k < 512) ? W_ih[((size_t)l * 2048 + n) * 512 + k]
                            : W_hh[((size_t)l * 2048 + n) * 512 + (k - 512)];
        Bpack[idx] = f2h(v);
    }
    for (int idx = tid0; idx < 2 * 2048; idx += stride) {
        int l = idx >> 11;
        int np = idx & 2047;
        int n = (np & 3) * 512 + (np >> 2);
        bsumv[idx] = b_ih[l * 2048 + n] + b_hh[l * 2048 + n];
    }
    for (int idx = tid0; idx < 3 * 512 * 512; idx += stride) {
        const float* w = idx < 262144 ? fc1w : (idx < 524288 ? fc2w : fc3w);
        fcw[idx] = f2h(w[idx & 262143]);
    }
}

// A buffers: [512][1024] f16: cols [0:512) = X (x / hsum / h0-as-X), [512:1024) = h
__global__ __launch_bounds__(256) void initbufs(
    const float* __restrict__ x, u16* __restrict__ A0_0, u16* __restrict__ A1_0,
    float* __restrict__ c0, float* __restrict__ c1, float* __restrict__ gb0)
{
    int stride = gridDim.x * blockDim.x;
    int tid0 = blockIdx.x * blockDim.x + threadIdx.x;
    for (int idx = tid0; idx < 512 * 512; idx += stride) {
        int row = idx >> 9, col = idx & 511;
        size_t b = (size_t)row * 1024;
        A0_0[b + col] = f2h(x[idx]);
        A1_0[b + 512 + col] = 0;     // h1(-1) = 0
        c0[idx] = 0.f;               // c layout [hcol][batch] — zero either way
        c1[idx] = 0.f;
    }
    for (int idx = tid0; idx < 1048576; idx += stride) gb0[idx] = 0.f;  // H-half of step 0
}

// --------------------------------------------------------------- lstm phase --
// 512 blocks x 256 thr (2/CU). Blocks 0..255: completion (gates = gbufR + X@W_x,
// epilogue). Blocks 256..511: partial (gbufW = H@W_h). Each role: 64 batch rows
// x 64 n'-cols, K=512 in 8 chunks of 64; depth-2 vmcnt pipeline, 3 LDS bufs x
// 16KB = 48KB. MFMA operands SWAPPED: acc[i][j] = n'-frag i x batch-frag j;
// lane's 4 regs = gates i,f,g,o of cell (batch = wm+j*16+fm, hcol = (wn+i*16)/4+q).
template <int IS_L1>
__global__ __launch_bounds__(256) void lstm_phase(
    const u16* __restrict__ Ax, const u16* __restrict__ Ah, int hoffH,
    const u16* __restrict__ Wc, const u16* __restrict__ Wp,
    const float* __restrict__ gbufR, float* __restrict__ gbufW,
    const float* __restrict__ bsumv, float* __restrict__ cbuf,
    u16* __restrict__ hdst, const u16* __restrict__ h0src,
    u16* __restrict__ hsumdst, u16* __restrict__ seqdst)
{
    __shared__ char smem[49152];   // 3 bufs x (A 8K | W 8K)

    const int id = blockIdx.x;
    const bool isPartial = id >= 256;
    const int rid = id & 255;
    const int xcd = rid & 7, slot = rid >> 3;
    const int nb = xcd * 4 + (slot & 3);   // 0..31
    const int rg = slot >> 2;              // 0..7
    const int n0 = nb * 64;
    const int row0 = rg * 64;
    const int tile = rg * 32 + nb;

    const u16* Abase = isPartial ? Ah : Ax;
    const int xoff = isPartial ? hoffH : 0;
    const u16* Wbase = isPartial ? Wp : Wc;

    const int tid = threadIdx.x;
    const int lane = tid & 63, wid = tid >> 6;
    const int wm = (wid >> 1) * 32, wn = (wid & 1) * 32;
    const int fm = lane & 15, q = lane >> 4;

    // staging: wave w stages 16B-units [w*128, w*128+128) of each 512-unit tile
    const int s0 = wid * 128 + lane, s1 = s0 + 64;
    const int r0s = s0 >> 3, c0s = ((s0 & 7) ^ (r0s & 7)) << 3;
    const int r1s = s1 >> 3, c1s = ((s1 & 7) ^ (r1s & 7)) << 3;
    const size_t aO0 = (size_t)(row0 + r0s) * 1024 + xoff + c0s;
    const size_t aO1 = (size_t)(row0 + r1s) * 1024 + xoff + c1s;
    const size_t bO0 = (size_t)(n0 + r0s) * 1024 + c0s;
    const size_t bO1 = (size_t)(n0 + r1s) * 1024 + c1s;
    const int d0 = wid * 2048, d1 = d0 + 1024;

    f32x4 acc[2][2];
    acc[0][0] = (f32x4)0.f; acc[0][1] = (f32x4)0.f;
    acc[1][0] = (f32x4)0.f; acc[1][1] = (f32x4)0.f;

    auto stage = [&](char* buf, int k0) {
        gl_lds16(Abase + aO0 + k0, buf + d0);
        gl_lds16(Abase + aO1 + k0, buf + d1);
        gl_lds16(Wbase + bO0 + k0, buf + 8192 + d0);
        gl_lds16(Wbase + bO1 + k0, buf + 8192 + d1);
    };

    char* p0 = smem;
    char* p1 = smem + 16384;
    char* p2 = smem + 32768;

    stage(p0, 0);
    stage(p1, 64);

    for (int c = 0; c < 8; ++c) {
        if (c < 7) asm volatile("s_waitcnt vmcnt(4)" ::: "memory");
        else       asm volatile("s_waitcnt vmcnt(0)" ::: "memory");
        __builtin_amdgcn_s_barrier();
        if (c < 6) stage(p2, (c + 2) * 64);   // overwrites buf consumed at c-1
        __builtin_amdgcn_sched_barrier(0);

        const u16* sA = (const u16*)p0;
        const u16* sB = (const u16*)(p0 + 8192);

#pragma unroll
        for (int kf = 0; kf < 2; ++kf) {
            const int cu = kf * 4 + q;
            f16x8 b0 = lds_read_sw(sB, wn + fm, cu);        // W rows wn..wn+15   (A-op)
            f16x8 b1 = lds_read_sw(sB, wn + 16 + fm, cu);   // W rows wn+16..+31
            f16x8 a0 = lds_read_sw(sA, wm + fm, cu);        // X rows wm..wm+15   (B-op)
            f16x8 a1 = lds_read_sw(sA, wm + 16 + fm, cu);   // X rows wm+16..+31
            // swapped: D = W · X^T ; acc[i][j] = n'-frag i, batch-frag j
            acc[0][0] = __builtin_amdgcn_mfma_f32_16x16x32_f16(b0, a0, acc[0][0], 0, 0, 0);
            acc[0][1] = __builtin_amdgcn_mfma_f32_16x16x32_f16(b0, a1, acc[0][1], 0, 0, 0);
            acc[1][0] = __builtin_amdgcn_mfma_f32_16x16x32_f16(b1, a0, acc[1][0], 0, 0, 0);
            acc[1][1] = __builtin_amdgcn_mfma_f32_16x16x32_f16(b1, a1, acc[1][1], 0, 0, 0);
        }

        char* t = p0; p0 = p1; p1 = p2; p2 = t;
    }

    // ---------------- partial role: dump fragments to gbufW, done --------------
    if (isPartial) {
        float* dst = gbufW + (size_t)tile * 4096 + wid * 1024 + lane * 4;
        *(f32x4*)(dst +   0) = acc[0][0];
        *(f32x4*)(dst + 256) = acc[0][1];
        *(f32x4*)(dst + 512) = acc[1][0];
        *(f32x4*)(dst + 768) = acc[1][1];
        return;
    }

    // ---------------- completion role: add partial, in-register LSTM cell ------
    {
        const float* src = gbufR + (size_t)tile * 4096 + wid * 1024 + lane * 4;
        acc[0][0] += *(const f32x4*)(src +   0);
        acc[0][1] += *(const f32x4*)(src + 256);
        acc[1][0] += *(const f32x4*)(src + 512);
        acc[1][1] += *(const f32x4*)(src + 768);
    }

    __syncthreads();               // staging drained; reuse smem as h buffer
    u16* hb = (u16*)smem;          // [64 batch][16 hcol] u16 = 2KB

#pragma unroll
    for (int i = 0; i < 2; ++i)
#pragma unroll
    for (int jj = 0; jj < 2; ++jj) {
        // lane's 4 regs = gates i,f,g,o of ONE cell:
        const int hcl = ((wn + i * 16) >> 2) + q;   // hcol local 0..15
        const int bl  = wm + jj * 16 + fm;          // batch local 0..63
        const float4 b4 = *(const float4*)&bsumv[n0 + wn + i * 16 + q * 4];
        float gi = acc[i][jj][0] + b4.x;
        float gf = acc[i][jj][1] + b4.y;
        float gg = acc[i][jj][2] + b4.z;
        float go = acc[i][jj][3] + b4.w;
        // c layout [hcol_global][batch_global] -> 64B-coalesced per 16-lane group
        const int cidx = ((n0 >> 2) + hcl) * 512 + (row0 + bl);
        float c_old = cbuf[cidx];
        float is = sigmoid_fast(gi);
        float fs = sigmoid_fast(gf);
        float os = sigmoid_fast(go);
        float gt = tanh_fast(gg);
        float cn = fs * c_old + is * gt;
        float hn = os * tanh_fast(cn);
        cbuf[cidx] = cn;
        hb[bl * 16 + hcl] = f2h(hn);
    }
    __syncthreads();

    // coalesced output pass: thread t -> batch = t>>2, 4 hcols = (t&3)*4
    {
        const int bl = tid >> 2;
        const int hc4 = (tid & 3) * 4;
        const int grow = row0 + bl;
        const int gh = (n0 >> 2) + hc4;
        ushort4 h4 = *(const ushort4*)&hb[bl * 16 + hc4];
        const size_t ab = (size_t)grow * 1024;
        if (!IS_L1) {
            // h0(t) -> X-slot of A1[cur]
            *(ushort4*)&hdst[ab + gh] = h4;
        } else {
            // h1(t) -> h-slot of A1[nxt]
            *(ushort4*)&hdst[ab + 512 + gh] = h4;
            // hsum(t) = h0(t) + h1(t) -> X-slot of A0[nxt] + seq output
            ushort4 h0v = *(const ushort4*)&h0src[ab + gh];
            ushort4 s4;
            s4.x = f2h(h2f(h0v.x) + h2f(h4.x));
            s4.y = f2h(h2f(h0v.y) + h2f(h4.y));
            s4.z = f2h(h2f(h0v.z) + h2f(h4.z));
            s4.w = f2h(h2f(h0v.w) + h2f(h4.w));
            *(ushort4*)&hsumdst[ab + gh] = s4;
            *(ushort4*)&seqdst[(size_t)grow * 512 + gh] = s4;
        }
    }
}

// ------------------------------------------------------------------- MLP -----
// Round-6 original (4096-block grid is TLP-saturated; keep proven form).
template <int RELU, int FINAL>
__global__ __launch_bounds__(256) void mlp_gemm(
    const u16* __restrict__ A, const u16* __restrict__ Bw, const float* __restrict__ bias,
    u16* __restrict__ yh, float* __restrict__ yf32)
{
    __shared__ char smem[36864];
    u16* sA = (u16*)smem;             // [64][72]
    u16* sB = (u16*)(smem + 9216);    // [128][72]

    const int tid = threadIdx.x;
    const int lane = tid & 63, wid = tid >> 6;
    const int row0 = blockIdx.y * 64;
    const int n0 = blockIdx.x * 128;
    const int wn = wid * 32;
    const int fm = lane & 15;
    const int fkbase = (lane >> 4) * 8;

    f32x4 acc[4][2];
#pragma unroll
    for (int m = 0; m < 4; ++m) { acc[m][0] = (f32x4)0.f; acc[m][1] = (f32x4)0.f; }

    for (int kk = 0; kk < 8; ++kk) {
        const int k0 = kk * 64;
        __syncthreads();
#pragma unroll
        for (int r = 0; r < 2; ++r) {
            int c = tid + r * 256;
            int row = c >> 3, cc = (c & 7) * 8;
            *(f16x8*)&sA[row * 72 + cc] = *(const f16x8*)&A[(size_t)(row0 + row) * 512 + k0 + cc];
        }
#pragma unroll
        for (int r = 0; r < 4; ++r) {
            int c = tid + r * 256;
            int row = c >> 3, cc = (c & 7) * 8;
            *(f16x8*)&sB[row * 72 + cc] = *(const f16x8*)&Bw[(size_t)(n0 + row) * 512 + k0 + cc];
        }
        __syncthreads();
#pragma unroll
        for (int kf = 0; kf < 2; ++kf) {
            const int kb = kf * 32 + fkbase;
            f16x8 b0 = *(const f16x8*)&sB[(wn + fm) * 72 + kb];
            f16x8 b1 = *(const f16x8*)&sB[(wn + 16 + fm) * 72 + kb];
#pragma unroll
            for (int m = 0; m < 4; ++m) {
                f16x8 ah = *(const f16x8*)&sA[(m * 16 + fm) * 72 + kb];
                acc[m][0] = __builtin_amdgcn_mfma_f32_16x16x32_f16(ah, b0, acc[m][0], 0, 0, 0);
                acc[m][1] = __builtin_amdgcn_mfma_f32_16x16x32_f16(ah, b1, acc[m][1], 0, 0, 0);
            }
        }
    }

    __syncthreads();
    float* sG = (float*)smem;  // [64][132]
#pragma unroll
    for (int m = 0; m < 4; ++m)
#pragma unroll
        for (int n = 0; n < 2; ++n)
#pragma unroll
            for (int r = 0; r < 4; ++r) {
                int row = m * 16 + (lane >> 4) * 4 + r;
                int col = wn + n * 16 + fm;
                sG[row * 132 + col] = acc[m][n][r];
            }
    __syncthreads();

    const int row = tid >> 2;
    const int cg = (tid & 3) * 32;
    const size_t r = (size_t)row0 + row;
#pragma unroll
    for (int c = cg; c < cg + 32; c += 4) {
        float4 g = *(const float4*)&sG[row * 132 + c];
        float4 b = *(const float4*)&bias[n0 + c];
        float v0 = g.x + b.x, v1 = g.y + b.y, v2 = g.z + b.z, v3 = g.w + b.w;
        if (RELU) {
            v0 = fmaxf(v0, 0.f); v1 = fmaxf(v1, 0.f); v2 = fmaxf(v2, 0.f); v3 = fmaxf(v3, 0.f);
        }
        if (!FINAL) {
            ushort4 p;
            p.x = f2h(v0); p.y = f2h(v1); p.z = f2h(v2); p.w = f2h(v3);
            *(ushort4*)&yh[r * 512 + n0 + c] = p;
        } else {
            int tt = (int)(r >> 9), bb = (int)(r & 511);  // seq row r = t*512 + b
            float4 o; o.x = v0; o.y = v1; o.z = v2; o.w = v3;
            *(float4*)&yf32[((size_t)bb * 128 + tt) * 512 + n0 + c] = o;
        }
    }
}

// ---------------------------------------------------------------- launch -----
extern "C" void kernel_launch(void* const* d_in, const int* in_sizes, int n_in,
                              void* d_out, int out_size, void* d_ws, size_t ws_size,
                              hipStream_t stream) {
    const float* x    = (const float*)d_in[0];
    const float* W_ih = (const float*)d_in[1];
    const float* W_hh = (const float*)d_in[2];
    const float* b_ih = (const float*)d_in[3];
    const float* b_hh = (const float*)d_in[4];
    const float* fc1w = (const float*)d_in[5];
    const float* fc1b = (const float*)d_in[6];
    const float* fc2w = (const float*)d_in[7];
    const float* fc2b = (const float*)d_in[8];
    const float* fc3w = (const float*)d_in[9];
    const float* fc3b = (const float*)d_in[10];

    char* ws = (char*)d_ws;
    u16* Bpack = (u16*)(ws);                          // 8,388,608 B
    u16* fcw   = (u16*)(ws + 8388608);                // 1,572,864 B
    float* bsum = (float*)(ws + 9961472);             // 16,384 B
    u16* A0[2] = { (u16*)(ws + 9977856),  (u16*)(ws + 11026432) };   // 1MB each
    u16* A1[2] = { (u16*)(ws + 12075008), (u16*)(ws + 13123584) };   // 1MB each
    float* c0 = (float*)(ws + 14172160);              // 1MB, layout [hcol][batch]
    float* c1 = (float*)(ws + 15220736);              // 1MB
    u16* seqb = (u16*)(ws + 20463616);                // 67,108,864 (reused as y2)
    // gb (LSTM-era) aliases the y1 (MLP-era) region — disjoint lifetimes.
    float* gb[2] = { (float*)(ws + 87572480), (float*)(ws + 87572480 + 4194304) };
    u16* y1   = (u16*)(ws + 87572480);                // 67,108,864
    float* out = (float*)d_out;

    prepack<<<dim3(512), dim3(256), 0, stream>>>(W_ih, W_hh, b_ih, b_hh, fc1w, fc2w, fc3w,
                                                 Bpack, bsum, fcw);
    initbufs<<<dim3(512), dim3(256), 0, stream>>>(x, A0[0], A1[0], c0, c1, gb[0]);

    const int LSTR = 2048 * 1024;
    for (int s = 0; s < 256; ++s) {
        int t = s >> 1, layer = s & 1, cur = t & 1, nxt = cur ^ 1;
        float* gR = gb[s & 1];
        float* gW = gb[(s + 1) & 1];
        if (!layer) {
            // completion: gates0(t) = gR + hsum(t-1)@Wih0 -> h0(t) into A1[cur] X-slot
            // partial:    gW = h1(t-1)@Whh1   (h1 from A1[cur] h-slot, W = layer1 k[512:1024))
            lstm_phase<0><<<dim3(512), dim3(256), 0, stream>>>(
                A0[cur], A1[cur], 512, Bpack, Bpack + LSTR + 512,
                gR, gW, bsum, c0,
                A1[cur], nullptr, nullptr, nullptr);
        } else {
            // completion: gates1(t) = gR + h0(t)@Wih1 -> h1(t) into A1[nxt] h-slot, hsum -> A0[nxt]
            // partial:    gW = h0(t)@Whh0     (h0 from A1[cur] X-slot, W = layer0 k[512:1024))
            lstm_phase<1><<<dim3(512), dim3(256), 0, stream>>>(
                A1[cur], A1[cur], 0, Bpack + LSTR, Bpack + 512,
                gR, gW, bsum + 2048, c1,
                A1[nxt], A1[cur], A0[nxt], seqb + (size_t)t * 262144);
        }
    }

    mlp_gemm<1, 0><<<dim3(4, 1024), dim3(256), 0, stream>>>(seqb, fcw, fc1b, y1, nullptr);
    mlp_gemm<1, 0><<<dim3(4, 1024), dim3(256), 0, stream>>>(y1, fcw + 512 * 512, fc2b, seqb, nullptr);
    mlp_gemm<0, 1><<<dim3(4, 1024), dim3(256), 0, stream>>>(seqb, fcw + 2 * 512 * 512, fc3b, nullptr, out);
}